// Round 8
// baseline (188.568 us; speedup 1.0000x reference)
//
#include <hip/hip_runtime.h>

// PairWeightedAveraging: m[1,S,N,Dm], z[1,N,N,Dz] -> out[1,S,N,Dm]
// S=256 N=512 Dm=64 Dz=128 H=8 HD=32
// Pipeline (all bf16 MFMA):
//  k0: pre-swizzle [Wm|Wg], Wo, and W'=znw*Wz (split hi/lo bf16) frag tables
//  k1a: bias b[h][i][j] = rs*(z.W'_h - mu*t1[h]) + cst[h] via split-bf16 MFMA
//  k1b: row softmax over j -> wf[h][jt][i][32] bf16 (K-panel layout)
//  k2a: LN(m) -> mn bf16
//  k2b: v = mn @ Wm -> vf[h][jt][np][32]
//  k3_fused: per block (i-tile 128, np-tile 64 = 2 s), loop ALL 8 heads:
//      o_h = w_h @ v_h (ring pipeline, counted vmcnt(3)); at head end:
//      g = sigmoid(mn@Wg_h) pointwise gate; LDS bounce og -> B-frag;
//      out_acc += Wo_h-frag @ og.  Writes out once.
//  R7->R8: LDS 57->52KB (bounce pad 40->32 + chunk-XOR swizzle) and
//  __launch_bounds__(256,3) -> 3 blocks/CU (was 2): latency-bound fix via TLP.

#define S_DIM 256
#define N_DIM 512
#define DM 64
#define DZ 128
#define NH 8
#define HD 32
#define HK 256
#define NP 8192  // S_DIM*HD
#define BKP 32   // K-panel depth
#define JT_N 16  // 512 / BKP

typedef unsigned int   u32;
typedef unsigned short u16;
typedef __bf16 bf16x8 __attribute__((ext_vector_type(8)));
typedef float  f32x4  __attribute__((ext_vector_type(4)));
typedef u32    u32x4  __attribute__((ext_vector_type(4)));

__device__ __forceinline__ u16 f2bf(float f) {
  u32 u = __builtin_bit_cast(u32, f);
  return (u16)((u + 0x7FFFu + ((u >> 16) & 1u)) >> 16);  // RNE
}
__device__ __forceinline__ float bf2f(u16 h) {
  u32 u = ((u32)h) << 16;
  return __builtin_bit_cast(float, u);
}
__device__ __forceinline__ u32 pack2(float a, float b) {
  return (u32)f2bf(a) | ((u32)f2bf(b) << 16);
}
__device__ __forceinline__ bf16x8 ld8(const u16* p) {
  return __builtin_bit_cast(bf16x8, *(const u32x4*)p);
}
__device__ __forceinline__ f32x4 mfma16(bf16x8 a, bf16x8 b, f32x4 c) {
  return __builtin_amdgcn_mfma_f32_16x16x32_bf16(a, b, c, 0, 0, 0);
}
__device__ __forceinline__ void gload_lds16(const void* gsrc, void* ldst) {
  __builtin_amdgcn_global_load_lds(
      (const __attribute__((address_space(1))) void*)gsrc,
      (__attribute__((address_space(3))) void*)ldst, 16, 0, 0);
}
// panel byte-offset swizzle (involution; permutes 16B chunks within 8 rows of 64B)
__device__ __forceinline__ int swz(int lin) { return lin ^ (((lin >> 7) & 3) << 4); }

#define BARRIER() do { asm volatile("" ::: "memory"); \
                       __builtin_amdgcn_s_barrier();  \
                       asm volatile("" ::: "memory"); } while (0)

// ---------------- k0: weight fragment tables ----------------
// wmg: [cb(32)][ks(2)][lane(64)][t(8)]  c=cb*16+(lane&15), k=ks*32+(lane>>4)*8+t
// wof: [cb(4)][ks(8)][lane(64)][t(8)]   c=cb*16+(lane&15), hk=ks*32+(lane>>4)*8+t
// wzf: [ks(4)][p(2)][lane(64)][t(8)]    h=lane&15 (<8), k=ks*32+(lane>>4)*8+t
// t1c: [0..7]=t1[h]=sum_c W'[c][h]; [8..15]=cst[h]=sum_c znb[c]*Wz[c][h]
__global__ __launch_bounds__(256) void k0_prep(
    const float* __restrict__ Wm, const float* __restrict__ Wg,
    const float* __restrict__ Wo, const float* __restrict__ znw,
    const float* __restrict__ znb, const float* __restrict__ Wz,
    u16* __restrict__ wmg, u16* __restrict__ wof,
    u16* __restrict__ wzf, float* __restrict__ t1c) {
  const int idx = blockIdx.x * 256 + threadIdx.x;
  if (idx < 32768) {
    const int t = idx & 7, lane = (idx >> 3) & 63, ks = (idx >> 9) & 1, cb = idx >> 10;
    const int c = cb * 16 + (lane & 15);
    const int k = ks * 32 + ((lane >> 4) & 3) * 8 + t;
    const float v = (c < HK) ? Wm[k * HK + c] : Wg[k * HK + (c - HK)];
    wmg[idx] = f2bf(v);
  } else if (idx < 32768 + 16384) {
    const int j = idx - 32768;
    const int t = j & 7, lane = (j >> 3) & 63, ks = (j >> 9) & 7, cb = j >> 12;
    const int c = cb * 16 + (lane & 15);
    const int hk = ks * 32 + ((lane >> 4) & 3) * 8 + t;
    wof[j] = f2bf(Wo[hk * DM + c]);
  } else if (idx < 49152 + 4096) {
    const int q = idx - 49152;
    const int t = q & 7, lane = (q >> 3) & 63, p = (q >> 9) & 1, ks = q >> 10;
    const int h = lane & 15;
    const int k = ks * 32 + ((lane >> 4) & 3) * 8 + t;
    u16 val = 0;
    if (h < NH) {
      const float wp = znw[k] * Wz[k * NH + h];
      const u16 hi = f2bf(wp);
      val = (p == 0) ? hi : f2bf(wp - bf2f(hi));
    }
    wzf[q] = val;
  } else if (idx < 49152 + 4096 + 16) {
    const int q = idx - 49152 - 4096;  // 0..15
    const int h = q & 7;
    float s = 0.f;
    for (int c = 0; c < DZ; ++c)
      s += ((q < 8) ? znw[c] : znb[c]) * Wz[c * NH + h];
    t1c[q] = s;
  }
}

// ---------------- k1a: bias via split-bf16 MFMA ----------------
__global__ __launch_bounds__(256) void k1a_bias(
    const float* __restrict__ z, const u16* __restrict__ wzf,
    const float* __restrict__ t1c, float* __restrict__ bws) {
  __shared__ float sB[NH][72];
  const int tid = threadIdx.x, lane = tid & 63, wv = tid >> 6;
  const int jb = blockIdx.x, i = blockIdx.y;
  const int jrow = jb * 64 + wv * 16 + (lane & 15);
  const float* zp = z + ((size_t)i * N_DIM + jrow) * DZ + ((lane >> 4) & 3) * 8;
  f32x4 acc = (f32x4){0.f, 0.f, 0.f, 0.f};
  float sum = 0.f, sq = 0.f;
  #pragma unroll
  for (int ks = 0; ks < 4; ++ks) {
    const float4 v0 = *(const float4*)(zp + ks * 32);
    const float4 v1 = *(const float4*)(zp + ks * 32 + 4);
    const float xs[8] = {v0.x, v0.y, v0.z, v0.w, v1.x, v1.y, v1.z, v1.w};
    bf16x8 zh, zl;
    #pragma unroll
    for (int t = 0; t < 8; ++t) {
      sum += xs[t]; sq += xs[t] * xs[t];
      const u16 h16 = f2bf(xs[t]);
      ((u16*)&zh)[t] = h16;
      ((u16*)&zl)[t] = f2bf(xs[t] - bf2f(h16));
    }
    const bf16x8 wh = ld8(wzf + (ks * 2 + 0) * 512 + lane * 8);
    const bf16x8 wl = ld8(wzf + (ks * 2 + 1) * 512 + lane * 8);
    acc = mfma16(zh, wh, acc);
    acc = mfma16(zl, wh, acc);
    acc = mfma16(zh, wl, acc);
  }
  sum += __shfl_xor(sum, 16, 64); sum += __shfl_xor(sum, 32, 64);
  sq  += __shfl_xor(sq, 16, 64);  sq  += __shfl_xor(sq, 32, 64);
  const float mu = sum * (1.f / DZ);
  const float rs = rsqrtf(sq * (1.f / DZ) - mu * mu + 1e-5f);
  const int h = lane & 15;
  const float t1 = t1c[h & 7], cst = t1c[8 + (h & 7)];
  #pragma unroll
  for (int rg = 0; rg < 4; ++rg) {
    const int r = ((lane >> 4) & 3) * 4 + rg;
    const float mur = __shfl(mu, r, 64);
    const float rsr = __shfl(rs, r, 64);
    const float bv = rsr * (acc[rg] - mur * t1) + cst;
    if (h < NH) sB[h][wv * 16 + r] = bv;
  }
  __syncthreads();
  #pragma unroll
  for (int q = 0; q < 2; ++q) {
    const int idx = tid + q * 256;
    const int hh = idx >> 6, jl = idx & 63;
    bws[((size_t)hh * N_DIM + i) * N_DIM + jb * 64 + jl] = sB[hh][jl];
  }
}

// ---------------- k1b: row softmax -> wf bf16 K-panel layout ----------------
__global__ __launch_bounds__(256) void k1b_softmax(
    const float* __restrict__ bws, u16* __restrict__ wout) {
  const int tid = threadIdx.x, lane = tid & 63, wv = tid >> 6;
  const int row = blockIdx.x * 4 + wv;  // row = h*512 + i
  const int h = row >> 9, i = row & 511;
  const float* bp = bws + (size_t)row * N_DIM + lane * 8;
  const float4 v0 = *(const float4*)bp;
  const float4 v1 = *(const float4*)(bp + 4);
  float xs[8] = {v0.x, v0.y, v0.z, v0.w, v1.x, v1.y, v1.z, v1.w};
  float mx = xs[0];
  #pragma unroll
  for (int t = 1; t < 8; ++t) mx = fmaxf(mx, xs[t]);
  #pragma unroll
  for (int off = 32; off; off >>= 1) mx = fmaxf(mx, __shfl_xor(mx, off, 64));
  float sm = 0.f;
  #pragma unroll
  for (int t = 0; t < 8; ++t) { xs[t] = __expf(xs[t] - mx); sm += xs[t]; }
  #pragma unroll
  for (int off = 32; off; off >>= 1) sm += __shfl_xor(sm, off, 64);
  const float inv = 1.f / sm;
  u32x4 pk;
  pk[0] = pack2(xs[0] * inv, xs[1] * inv);
  pk[1] = pack2(xs[2] * inv, xs[3] * inv);
  pk[2] = pack2(xs[4] * inv, xs[5] * inv);
  pk[3] = pack2(xs[6] * inv, xs[7] * inv);
  *(u32x4*)(wout + (((size_t)(h * JT_N + (lane >> 2)) * N_DIM + i) << 5)
            + (lane & 3) * 8) = pk;
}

// ---------------- k2a: LN(m) -> mn bf16 [r=(s,n)][64] ----------------
__global__ __launch_bounds__(256) void k2a_ln_m(
    const float* __restrict__ m, const float* __restrict__ mnw,
    const float* __restrict__ mnb, u16* __restrict__ mn) {
  __shared__ float sw[DM], sb[DM];
  const int tid = threadIdx.x;
  if (tid < DM) { sw[tid] = mnw[tid]; sb[tid] = mnb[tid]; }
  __syncthreads();
  const size_t r = (size_t)blockIdx.x * 256 + tid;
  const float4* mp = (const float4*)(m + r * DM);
  float4 arr[16];
  float sum = 0.f, sq = 0.f;
  #pragma unroll
  for (int q = 0; q < 16; ++q) {
    float4 v = mp[q]; arr[q] = v;
    sum += v.x + v.y + v.z + v.w;
    sq  += v.x * v.x + v.y * v.y + v.z * v.z + v.w * v.w;
  }
  const float mu = sum * (1.f / DM);
  const float rs = rsqrtf(sq * (1.f / DM) - mu * mu + 1e-5f);
  uint4* op = (uint4*)(mn + r * DM);
  #pragma unroll
  for (int q = 0; q < 8; ++q) {
    const float4 a = arr[2 * q], b = arr[2 * q + 1];
    const int c0 = q * 8;
    const float y0 = (a.x - mu) * rs * sw[c0 + 0] + sb[c0 + 0];
    const float y1 = (a.y - mu) * rs * sw[c0 + 1] + sb[c0 + 1];
    const float y2 = (a.z - mu) * rs * sw[c0 + 2] + sb[c0 + 2];
    const float y3 = (a.w - mu) * rs * sw[c0 + 3] + sb[c0 + 3];
    const float y4 = (b.x - mu) * rs * sw[c0 + 4] + sb[c0 + 4];
    const float y5 = (b.y - mu) * rs * sw[c0 + 5] + sb[c0 + 5];
    const float y6 = (b.z - mu) * rs * sw[c0 + 6] + sb[c0 + 6];
    const float y7 = (b.w - mu) * rs * sw[c0 + 7] + sb[c0 + 7];
    uint4 u;
    u.x = pack2(y0, y1); u.y = pack2(y2, y3);
    u.z = pack2(y4, y5); u.w = pack2(y6, y7);
    op[q] = u;
  }
}

// ---------------- k2b: v = mn @ Wm -> vf[h][jt][np][32] ----------------
__global__ __launch_bounds__(256) void k2b_proj(
    const u16* __restrict__ mn, const u16* __restrict__ wmg,
    u16* __restrict__ vf) {
  const int tid = threadIdx.x, lane = tid & 63, wv = tid >> 6;
  const int rbase = (blockIdx.x * 4 + wv) * 16;
  const u16* ap = mn + (size_t)(rbase + (lane & 15)) * DM + ((lane >> 4) & 3) * 8;
  const bf16x8 a0 = ld8(ap);
  const bf16x8 a1 = ld8(ap + 32);
  const u16* bp = wmg + lane * 8;
  const int r0 = rbase + ((lane >> 4) & 3) * 4;
  const int s0 = r0 >> 9;
  const int j0 = r0 & 511;

  f32x4 acc[16];
  #pragma unroll
  for (int cb = 0; cb < 16; ++cb) acc[cb] = (f32x4){0.f, 0.f, 0.f, 0.f};
  #pragma unroll
  for (int cb = 0; cb < 16; ++cb) {
    acc[cb] = mfma16(a0, ld8(bp + cb * 1024), acc[cb]);
    acc[cb] = mfma16(a1, ld8(bp + cb * 1024 + 512), acc[cb]);
  }
  #pragma unroll
  for (int cb = 0; cb < 16; ++cb) {
    const int c = cb * 16 + (lane & 15);
    const int h = c >> 5, k = c & 31;
    const int np = s0 * HD + k;
    const size_t idx = (((size_t)(h * JT_N + (j0 >> 5)) * NP + np) << 5) + (j0 & 31);
    ushort4 pk;
    pk.x = f2bf(acc[cb][0]); pk.y = f2bf(acc[cb][1]);
    pk.z = f2bf(acc[cb][2]); pk.w = f2bf(acc[cb][3]);
    *(ushort4*)(vf + idx) = pk;
  }
}

// ---------------- k3_fused: o = w@v over all heads + gate + Wo projection ----
// Block: i-tile 128 (yt), np-tile 64 = 2 s (xt). 4 waves: (wr: i-half, wc: s).
// XCD map: xcd = bid&7 owns np-tiles [xcd*16,(xcd+1)*16); the 4 i-tiles
// sharing each vf panel are consecutive on one XCD.
// LDS 52KB -> 3 blocks/CU (TLP covers HBM first-touch latency).
__global__ __launch_bounds__(256, 3) void k3_fused(
    const u16* __restrict__ wf, const u16* __restrict__ vf,
    const u16* __restrict__ mn, const u16* __restrict__ wmg,
    const u16* __restrict__ wof, float* __restrict__ out) {
  __shared__ __attribute__((aligned(16))) u16 ring[3][6144];  // A 8KB | B 4KB
  __shared__ __attribute__((aligned(16))) u16 sbnc[4][64 * 32];  // per-wave bounce
  const int tid = threadIdx.x, lane = tid & 63, wv = tid >> 6;
  const int q = (lane >> 4) & 3;
  const int wr = wv >> 1, wc = wv & 1;
  const int bid = blockIdx.x;            // 0..511
  const int xcd = bid & 7, j = bid >> 3; // j 0..63
  const int xt = xcd * 16 + (j >> 2);    // np-tile 0..127 (partitioned by XCD)
  const int yt = j & 3;                  // i-tile 0..3 (consecutive per panel)
  const int i0 = yt * 128;
  const int n0 = xt * 64;
  const int s  = xt * 2 + wc;

  // staging offsets (per wave): A 2KB (2 loads), B 1KB (1 load)
  const int sbA0 = wv * 2048, sbA1 = wv * 2048 + 1024, sbB = wv * 1024;
  const int soA0 = swz(sbA0 + lane * 16);
  const int soA1 = swz(sbA1 + lane * 16);
  const int soB  = swz(sbB + lane * 16);

  // LDS read offsets
  int offA[4], offB[2];
  #pragma unroll
  for (int f = 0; f < 4; ++f)
    offA[f] = swz((wr * 64 + f * 16 + (lane & 15)) * 64 + q * 16);
  #pragma unroll
  for (int f = 0; f < 2; ++f)
    offB[f] = 8192 + swz((wc * 32 + f * 16 + (lane & 15)) * 64 + q * 16);

  f32x4 acc[4][2];   // o fragments: [fi][fn]; col=lane&15 -> i, row -> k
  f32x4 oacc[4][4];  // out fragments: [cn][fi]; col -> i, row -> c
  #pragma unroll
  for (int a = 0; a < 4; ++a) {
    #pragma unroll
    for (int b = 0; b < 2; ++b) acc[a][b] = (f32x4){0.f, 0.f, 0.f, 0.f};
    #pragma unroll
    for (int b = 0; b < 4; ++b) oacc[a][b] = (f32x4){0.f, 0.f, 0.f, 0.f};
  }

#define STAGE(tt, slot)                                                    \
  do {                                                                     \
    const char* pA_ = (const char*)(wf + ((size_t)(tt) * 512 + i0) * 32);  \
    const char* pB_ = (const char*)(vf + ((size_t)(tt) * 8192 + n0) * 32); \
    char* dA_ = (char*)&ring[(slot)][0];                                   \
    char* dB_ = (char*)&ring[(slot)][4096];                                \
    gload_lds16(pA_ + soA0, dA_ + sbA0);                                   \
    gload_lds16(pA_ + soA1, dA_ + sbA1);                                   \
    gload_lds16(pB_ + soB,  dB_ + sbB);                                    \
  } while (0)

#define COMPUTE(slot)                                                      \
  do {                                                                     \
    const char* cS_ = (const char*)&ring[(slot)][0];                       \
    bf16x8 af_[4], bf_[2];                                                 \
    _Pragma("unroll")                                                      \
    for (int f = 0; f < 4; ++f) af_[f] = ld8((const u16*)(cS_ + offA[f])); \
    _Pragma("unroll")                                                      \
    for (int f = 0; f < 2; ++f) bf_[f] = ld8((const u16*)(cS_ + offB[f])); \
    _Pragma("unroll")                                                      \
    for (int fi = 0; fi < 4; ++fi)                                         \
      _Pragma("unroll")                                                    \
      for (int fn = 0; fn < 2; ++fn)                                       \
        acc[fi][fn] = mfma16(bf_[fn], af_[fi], acc[fi][fn]);               \
  } while (0)

  // per-head interlude: gate o with sigmoid(mn@Wg_h), bounce, project into oacc
  // bounce addressing (u16 units): row*32 + (col ^ ((row&3)<<3))  — chunk-XOR
  // swizzle applied identically on write (8B) and read (16B): 2-way banks.
#define INTERLUDE(hh)                                                      \
  do {                                                                     \
    bf16x8 wg_[2][2], mnf_[4][2];                                          \
    _Pragma("unroll")                                                      \
    for (int k2 = 0; k2 < 2; ++k2)                                         \
      _Pragma("unroll")                                                    \
      for (int kk = 0; kk < 2; ++kk)                                       \
        wg_[k2][kk] = ld8(wmg + ((16 + (hh) * 2 + k2) * 2 + kk) * 512 + lane * 8); \
    _Pragma("unroll")                                                      \
    for (int fi = 0; fi < 4; ++fi) {                                       \
      const u16* mp_ = mn + (size_t)(s * N_DIM + i0 + wr * 64 + fi * 16    \
                                     + (lane & 15)) * DM + q * 8;          \
      mnf_[fi][0] = ld8(mp_);                                              \
      mnf_[fi][1] = ld8(mp_ + 32);                                         \
    }                                                                      \
    u16* bb_ = &sbnc[wv][0];                                               \
    _Pragma("unroll")                                                      \
    for (int fi = 0; fi < 4; ++fi) {                                       \
      const int row_ = fi * 16 + (lane & 15);                              \
      _Pragma("unroll")                                                    \
      for (int fn = 0; fn < 2; ++fn) {                                     \
        f32x4 ga_ = (f32x4){0.f, 0.f, 0.f, 0.f};                           \
        ga_ = mfma16(wg_[fn][0], mnf_[fi][0], ga_);                        \
        ga_ = mfma16(wg_[fn][1], mnf_[fi][1], ga_);                        \
        ushort4 pk_;                                                       \
        pk_.x = f2bf(acc[fi][fn][0] / (1.f + __expf(-ga_[0])));            \
        pk_.y = f2bf(acc[fi][fn][1] / (1.f + __expf(-ga_[1])));            \
        pk_.z = f2bf(acc[fi][fn][2] / (1.f + __expf(-ga_[2])));            \
        pk_.w = f2bf(acc[fi][fn][3] / (1.f + __expf(-ga_[3])));            \
        *(ushort4*)(bb_ + row_ * 32                                        \
                    + ((fn * 16 + q * 4) ^ ((row_ & 3) << 3))) = pk_;      \
        acc[fi][fn] = (f32x4){0.f, 0.f, 0.f, 0.f};                         \
      }                                                                    \
    }                                                                      \
    asm volatile("s_waitcnt lgkmcnt(0)" ::: "memory");                     \
    __builtin_amdgcn_sched_barrier(0);                                     \
    bf16x8 ogf_[4], wo_[4];                                                \
    _Pragma("unroll")                                                      \
    for (int fi = 0; fi < 4; ++fi) {                                       \
      const int row_ = fi * 16 + (lane & 15);                              \
      ogf_[fi] = ld8(bb_ + row_ * 32 + ((q * 8) ^ ((row_ & 3) << 3)));     \
    }                                                                      \
    _Pragma("unroll")                                                      \
    for (int cn = 0; cn < 4; ++cn)                                         \
      wo_[cn] = ld8(wof + ((cn * 8 + (hh)) * 64 + lane) * 8);              \
    _Pragma("unroll")                                                      \
    for (int cn = 0; cn < 4; ++cn)                                         \
      _Pragma("unroll")                                                    \
      for (int fi = 0; fi < 4; ++fi)                                       \
        oacc[cn][fi] = mfma16(wo_[cn], ogf_[fi], oacc[cn][fi]);            \
  } while (0)

  // prologue: tiles 0,1 in flight (t enumerates (h,jt) = t>>4, t&15)
  STAGE(0, 0);
  STAGE(1, 1);
  for (int t = 0; t < 127; ++t) {
    asm volatile("s_waitcnt vmcnt(3)" ::: "memory");  // tile t landed
    BARRIER();
    if (t < 126) STAGE(t + 2, (t + 2) % 3);
    COMPUTE(t % 3);
    if ((t & 15) == 15) INTERLUDE(t >> 4);  // heads 0..6
  }
  asm volatile("s_waitcnt vmcnt(0)" ::: "memory");
  BARRIER();
  COMPUTE(127 % 3);
  INTERLUDE(7);
#undef STAGE
#undef COMPUTE
#undef INTERLUDE

  // epilogue: write out[s][i][c] f32 (col=lane&15 -> i, row q*4+rg -> c)
  #pragma unroll
  for (int cn = 0; cn < 4; ++cn) {
    #pragma unroll
    for (int fi = 0; fi < 4; ++fi) {
      float* op = out + (size_t)(s * N_DIM + i0 + wr * 64 + fi * 16
                                 + (lane & 15)) * DM + cn * 16 + q * 4;
      *(f32x4*)op = oacc[cn][fi];
    }
  }
}

extern "C" void kernel_launch(void* const* d_in, const int* in_sizes, int n_in,
                              void* d_out, int out_size, void* d_ws, size_t ws_size,
                              hipStream_t stream) {
  const float* m   = (const float*)d_in[0];
  const float* z   = (const float*)d_in[1];
  const float* mnw = (const float*)d_in[2];
  const float* mnb = (const float*)d_in[3];
  const float* znw = (const float*)d_in[4];
  const float* znb = (const float*)d_in[5];
  const float* Wm  = (const float*)d_in[6];
  const float* Wg  = (const float*)d_in[7];
  const float* Wz  = (const float*)d_in[8];
  const float* Wo  = (const float*)d_in[9];
  float* out = (float*)d_out;
  char* ws = (char*)d_ws;

  // ws layout (bytes): wf 4MiB | vf 64MiB | (free 64MiB) | mn 16MiB |
  //                    wmg 64KiB | wof 32KiB | wzf 8KiB | t1c 64B
  // bws (8MiB f32) overlaps mn: k1a writes / k1b reads it BEFORE k2a writes mn.
  u16*   wbuf = (u16*)(ws);
  u16*   vf   = (u16*)(ws + ((size_t)4   << 20));
  u16*   mn   = (u16*)(ws + ((size_t)132 << 20));
  float* bws  = (float*)(ws + ((size_t)132 << 20));
  u16*   wmg  = (u16*)(ws + ((size_t)148 << 20));
  u16*   wof  = (u16*)(ws + ((size_t)148 << 20) + 65536);
  u16*   wzf  = (u16*)(ws + ((size_t)148 << 20) + 98304);
  float* t1c  = (float*)(ws + ((size_t)148 << 20) + 106496);

  k0_prep<<<209, 256, 0, stream>>>(Wm, Wg, Wo, znw, znb, Wz, wmg, wof, wzf, t1c);
  k1a_bias<<<dim3(8, 512), 256, 0, stream>>>(z, wzf, t1c, bws);
  k1b_softmax<<<1024, 256, 0, stream>>>(bws, wbuf);
  k2a_ln_m<<<512, 256, 0, stream>>>(m, mnw, mnb, mn);
  k2b_proj<<<2048, 256, 0, stream>>>(mn, wmg, vf);
  k3_fused<<<512, 256, 0, stream>>>(wbuf, vf, mn, wmg, wof, out);
}

// Round 9
// 176.793 us; speedup vs baseline: 1.0666x; 1.0666x over previous
//
#include <hip/hip_runtime.h>

// PairWeightedAveraging: m[1,S,N,Dm], z[1,N,N,Dz] -> out[1,S,N,Dm]
// S=256 N=512 Dm=64 Dz=128 H=8 HD=32
// Pipeline (all bf16 MFMA):
//  k0: pre-swizzle [Wm|Wg], Wo, and W'=znw*Wz (split hi/lo bf16) frag tables
//  k1a: bias b[h][i][j] = rs*(z.W'_h - mu*t1[h]) + cst[h] via split-bf16 MFMA
//  k1b: row softmax over j -> wf[h][jt][i][32] bf16 (K-panel layout)
//  k2a: LN(m) -> mn bf16
//  k2b: v = mn @ Wm -> vf[h][jt][np][32]
//  k3_fused: per block (i-tile 128, np-tile 64 = 2 s), loop ALL 8 heads:
//      o_h = w_h @ v_h (5-slot ring, prefetch distance 4, vmcnt(9) -- never
//      drains in-loop); at head end: g = sigmoid(mn@Wg_h) pointwise gate;
//      LDS bounce og -> B-frag; out_acc += Wo_h-frag @ og. Writes out once.
//  R8->R9: grid is 512 blocks = exactly 2/CU, so TLP is fixed; the fix is
//  ILP: ring 3->5 slots (distance 2->4 covers ~900cy HBM latency). Bounce
//  reverted to padded layout (pad 36), launch_bounds(256,2).

#define S_DIM 256
#define N_DIM 512
#define DM 64
#define DZ 128
#define NH 8
#define HD 32
#define HK 256
#define NP 8192  // S_DIM*HD
#define BKP 32   // K-panel depth
#define JT_N 16  // 512 / BKP

typedef unsigned int   u32;
typedef unsigned short u16;
typedef __bf16 bf16x8 __attribute__((ext_vector_type(8)));
typedef float  f32x4  __attribute__((ext_vector_type(4)));
typedef u32    u32x4  __attribute__((ext_vector_type(4)));

__device__ __forceinline__ u16 f2bf(float f) {
  u32 u = __builtin_bit_cast(u32, f);
  return (u16)((u + 0x7FFFu + ((u >> 16) & 1u)) >> 16);  // RNE
}
__device__ __forceinline__ float bf2f(u16 h) {
  u32 u = ((u32)h) << 16;
  return __builtin_bit_cast(float, u);
}
__device__ __forceinline__ u32 pack2(float a, float b) {
  return (u32)f2bf(a) | ((u32)f2bf(b) << 16);
}
__device__ __forceinline__ bf16x8 ld8(const u16* p) {
  return __builtin_bit_cast(bf16x8, *(const u32x4*)p);
}
__device__ __forceinline__ f32x4 mfma16(bf16x8 a, bf16x8 b, f32x4 c) {
  return __builtin_amdgcn_mfma_f32_16x16x32_bf16(a, b, c, 0, 0, 0);
}
__device__ __forceinline__ void gload_lds16(const void* gsrc, void* ldst) {
  __builtin_amdgcn_global_load_lds(
      (const __attribute__((address_space(1))) void*)gsrc,
      (__attribute__((address_space(3))) void*)ldst, 16, 0, 0);
}
// panel byte-offset swizzle (involution; permutes 16B chunks within 8 rows of 64B)
__device__ __forceinline__ int swz(int lin) { return lin ^ (((lin >> 7) & 3) << 4); }

#define BARRIER() do { asm volatile("" ::: "memory"); \
                       __builtin_amdgcn_s_barrier();  \
                       asm volatile("" ::: "memory"); } while (0)

// ---------------- k0: weight fragment tables ----------------
// wmg: [cb(32)][ks(2)][lane(64)][t(8)]  c=cb*16+(lane&15), k=ks*32+(lane>>4)*8+t
// wof: [cb(4)][ks(8)][lane(64)][t(8)]   c=cb*16+(lane&15), hk=ks*32+(lane>>4)*8+t
// wzf: [ks(4)][p(2)][lane(64)][t(8)]    h=lane&15 (<8), k=ks*32+(lane>>4)*8+t
// t1c: [0..7]=t1[h]=sum_c W'[c][h]; [8..15]=cst[h]=sum_c znb[c]*Wz[c][h]
__global__ __launch_bounds__(256) void k0_prep(
    const float* __restrict__ Wm, const float* __restrict__ Wg,
    const float* __restrict__ Wo, const float* __restrict__ znw,
    const float* __restrict__ znb, const float* __restrict__ Wz,
    u16* __restrict__ wmg, u16* __restrict__ wof,
    u16* __restrict__ wzf, float* __restrict__ t1c) {
  const int idx = blockIdx.x * 256 + threadIdx.x;
  if (idx < 32768) {
    const int t = idx & 7, lane = (idx >> 3) & 63, ks = (idx >> 9) & 1, cb = idx >> 10;
    const int c = cb * 16 + (lane & 15);
    const int k = ks * 32 + ((lane >> 4) & 3) * 8 + t;
    const float v = (c < HK) ? Wm[k * HK + c] : Wg[k * HK + (c - HK)];
    wmg[idx] = f2bf(v);
  } else if (idx < 32768 + 16384) {
    const int j = idx - 32768;
    const int t = j & 7, lane = (j >> 3) & 63, ks = (j >> 9) & 7, cb = j >> 12;
    const int c = cb * 16 + (lane & 15);
    const int hk = ks * 32 + ((lane >> 4) & 3) * 8 + t;
    wof[j] = f2bf(Wo[hk * DM + c]);
  } else if (idx < 49152 + 4096) {
    const int q = idx - 49152;
    const int t = q & 7, lane = (q >> 3) & 63, p = (q >> 9) & 1, ks = q >> 10;
    const int h = lane & 15;
    const int k = ks * 32 + ((lane >> 4) & 3) * 8 + t;
    u16 val = 0;
    if (h < NH) {
      const float wp = znw[k] * Wz[k * NH + h];
      const u16 hi = f2bf(wp);
      val = (p == 0) ? hi : f2bf(wp - bf2f(hi));
    }
    wzf[q] = val;
  } else if (idx < 49152 + 4096 + 16) {
    const int q = idx - 49152 - 4096;  // 0..15
    const int h = q & 7;
    float s = 0.f;
    for (int c = 0; c < DZ; ++c)
      s += ((q < 8) ? znw[c] : znb[c]) * Wz[c * NH + h];
    t1c[q] = s;
  }
}

// ---------------- k1a: bias via split-bf16 MFMA ----------------
__global__ __launch_bounds__(256) void k1a_bias(
    const float* __restrict__ z, const u16* __restrict__ wzf,
    const float* __restrict__ t1c, float* __restrict__ bws) {
  __shared__ float sB[NH][72];
  const int tid = threadIdx.x, lane = tid & 63, wv = tid >> 6;
  const int jb = blockIdx.x, i = blockIdx.y;
  const int jrow = jb * 64 + wv * 16 + (lane & 15);
  const float* zp = z + ((size_t)i * N_DIM + jrow) * DZ + ((lane >> 4) & 3) * 8;
  f32x4 acc = (f32x4){0.f, 0.f, 0.f, 0.f};
  float sum = 0.f, sq = 0.f;
  #pragma unroll
  for (int ks = 0; ks < 4; ++ks) {
    const float4 v0 = *(const float4*)(zp + ks * 32);
    const float4 v1 = *(const float4*)(zp + ks * 32 + 4);
    const float xs[8] = {v0.x, v0.y, v0.z, v0.w, v1.x, v1.y, v1.z, v1.w};
    bf16x8 zh, zl;
    #pragma unroll
    for (int t = 0; t < 8; ++t) {
      sum += xs[t]; sq += xs[t] * xs[t];
      const u16 h16 = f2bf(xs[t]);
      ((u16*)&zh)[t] = h16;
      ((u16*)&zl)[t] = f2bf(xs[t] - bf2f(h16));
    }
    const bf16x8 wh = ld8(wzf + (ks * 2 + 0) * 512 + lane * 8);
    const bf16x8 wl = ld8(wzf + (ks * 2 + 1) * 512 + lane * 8);
    acc = mfma16(zh, wh, acc);
    acc = mfma16(zl, wh, acc);
    acc = mfma16(zh, wl, acc);
  }
  sum += __shfl_xor(sum, 16, 64); sum += __shfl_xor(sum, 32, 64);
  sq  += __shfl_xor(sq, 16, 64);  sq  += __shfl_xor(sq, 32, 64);
  const float mu = sum * (1.f / DZ);
  const float rs = rsqrtf(sq * (1.f / DZ) - mu * mu + 1e-5f);
  const int h = lane & 15;
  const float t1 = t1c[h & 7], cst = t1c[8 + (h & 7)];
  #pragma unroll
  for (int rg = 0; rg < 4; ++rg) {
    const int r = ((lane >> 4) & 3) * 4 + rg;
    const float mur = __shfl(mu, r, 64);
    const float rsr = __shfl(rs, r, 64);
    const float bv = rsr * (acc[rg] - mur * t1) + cst;
    if (h < NH) sB[h][wv * 16 + r] = bv;
  }
  __syncthreads();
  #pragma unroll
  for (int q = 0; q < 2; ++q) {
    const int idx = tid + q * 256;
    const int hh = idx >> 6, jl = idx & 63;
    bws[((size_t)hh * N_DIM + i) * N_DIM + jb * 64 + jl] = sB[hh][jl];
  }
}

// ---------------- k1b: row softmax -> wf bf16 K-panel layout ----------------
__global__ __launch_bounds__(256) void k1b_softmax(
    const float* __restrict__ bws, u16* __restrict__ wout) {
  const int tid = threadIdx.x, lane = tid & 63, wv = tid >> 6;
  const int row = blockIdx.x * 4 + wv;  // row = h*512 + i
  const int h = row >> 9, i = row & 511;
  const float* bp = bws + (size_t)row * N_DIM + lane * 8;
  const float4 v0 = *(const float4*)bp;
  const float4 v1 = *(const float4*)(bp + 4);
  float xs[8] = {v0.x, v0.y, v0.z, v0.w, v1.x, v1.y, v1.z, v1.w};
  float mx = xs[0];
  #pragma unroll
  for (int t = 1; t < 8; ++t) mx = fmaxf(mx, xs[t]);
  #pragma unroll
  for (int off = 32; off; off >>= 1) mx = fmaxf(mx, __shfl_xor(mx, off, 64));
  float sm = 0.f;
  #pragma unroll
  for (int t = 0; t < 8; ++t) { xs[t] = __expf(xs[t] - mx); sm += xs[t]; }
  #pragma unroll
  for (int off = 32; off; off >>= 1) sm += __shfl_xor(sm, off, 64);
  const float inv = 1.f / sm;
  u32x4 pk;
  pk[0] = pack2(xs[0] * inv, xs[1] * inv);
  pk[1] = pack2(xs[2] * inv, xs[3] * inv);
  pk[2] = pack2(xs[4] * inv, xs[5] * inv);
  pk[3] = pack2(xs[6] * inv, xs[7] * inv);
  *(u32x4*)(wout + (((size_t)(h * JT_N + (lane >> 2)) * N_DIM + i) << 5)
            + (lane & 3) * 8) = pk;
}

// ---------------- k2a: LN(m) -> mn bf16 [r=(s,n)][64] ----------------
__global__ __launch_bounds__(256) void k2a_ln_m(
    const float* __restrict__ m, const float* __restrict__ mnw,
    const float* __restrict__ mnb, u16* __restrict__ mn) {
  __shared__ float sw[DM], sb[DM];
  const int tid = threadIdx.x;
  if (tid < DM) { sw[tid] = mnw[tid]; sb[tid] = mnb[tid]; }
  __syncthreads();
  const size_t r = (size_t)blockIdx.x * 256 + tid;
  const float4* mp = (const float4*)(m + r * DM);
  float4 arr[16];
  float sum = 0.f, sq = 0.f;
  #pragma unroll
  for (int q = 0; q < 16; ++q) {
    float4 v = mp[q]; arr[q] = v;
    sum += v.x + v.y + v.z + v.w;
    sq  += v.x * v.x + v.y * v.y + v.z * v.z + v.w * v.w;
  }
  const float mu = sum * (1.f / DM);
  const float rs = rsqrtf(sq * (1.f / DM) - mu * mu + 1e-5f);
  uint4* op = (uint4*)(mn + r * DM);
  #pragma unroll
  for (int q = 0; q < 8; ++q) {
    const float4 a = arr[2 * q], b = arr[2 * q + 1];
    const int c0 = q * 8;
    const float y0 = (a.x - mu) * rs * sw[c0 + 0] + sb[c0 + 0];
    const float y1 = (a.y - mu) * rs * sw[c0 + 1] + sb[c0 + 1];
    const float y2 = (a.z - mu) * rs * sw[c0 + 2] + sb[c0 + 2];
    const float y3 = (a.w - mu) * rs * sw[c0 + 3] + sb[c0 + 3];
    const float y4 = (b.x - mu) * rs * sw[c0 + 4] + sb[c0 + 4];
    const float y5 = (b.y - mu) * rs * sw[c0 + 5] + sb[c0 + 5];
    const float y6 = (b.z - mu) * rs * sw[c0 + 6] + sb[c0 + 6];
    const float y7 = (b.w - mu) * rs * sw[c0 + 7] + sb[c0 + 7];
    uint4 u;
    u.x = pack2(y0, y1); u.y = pack2(y2, y3);
    u.z = pack2(y4, y5); u.w = pack2(y6, y7);
    op[q] = u;
  }
}

// ---------------- k2b: v = mn @ Wm -> vf[h][jt][np][32] ----------------
__global__ __launch_bounds__(256) void k2b_proj(
    const u16* __restrict__ mn, const u16* __restrict__ wmg,
    u16* __restrict__ vf) {
  const int tid = threadIdx.x, lane = tid & 63, wv = tid >> 6;
  const int rbase = (blockIdx.x * 4 + wv) * 16;
  const u16* ap = mn + (size_t)(rbase + (lane & 15)) * DM + ((lane >> 4) & 3) * 8;
  const bf16x8 a0 = ld8(ap);
  const bf16x8 a1 = ld8(ap + 32);
  const u16* bp = wmg + lane * 8;
  const int r0 = rbase + ((lane >> 4) & 3) * 4;
  const int s0 = r0 >> 9;
  const int j0 = r0 & 511;

  f32x4 acc[16];
  #pragma unroll
  for (int cb = 0; cb < 16; ++cb) acc[cb] = (f32x4){0.f, 0.f, 0.f, 0.f};
  #pragma unroll
  for (int cb = 0; cb < 16; ++cb) {
    acc[cb] = mfma16(a0, ld8(bp + cb * 1024), acc[cb]);
    acc[cb] = mfma16(a1, ld8(bp + cb * 1024 + 512), acc[cb]);
  }
  #pragma unroll
  for (int cb = 0; cb < 16; ++cb) {
    const int c = cb * 16 + (lane & 15);
    const int h = c >> 5, k = c & 31;
    const int np = s0 * HD + k;
    const size_t idx = (((size_t)(h * JT_N + (j0 >> 5)) * NP + np) << 5) + (j0 & 31);
    ushort4 pk;
    pk.x = f2bf(acc[cb][0]); pk.y = f2bf(acc[cb][1]);
    pk.z = f2bf(acc[cb][2]); pk.w = f2bf(acc[cb][3]);
    *(ushort4*)(vf + idx) = pk;
  }
}

// ---------------- k3_fused: o = w@v over all heads + gate + Wo projection ----
// Block: i-tile 128 (yt), np-tile 64 = 2 s (xt). 4 waves: (wr: i-half, wc: s).
// XCD map: xcd = bid&7 owns np-tiles [xcd*16,(xcd+1)*16); the 4 i-tiles
// sharing each vf panel are consecutive on one XCD.
// 5-slot ring, prefetch distance 4, in-loop wait vmcnt(9) (3 stages in
// flight, never drained); tail peels vmcnt(6)/(3)/(0).  LDS 78KB, 2 blk/CU.
__global__ __launch_bounds__(256, 2) void k3_fused(
    const u16* __restrict__ wf, const u16* __restrict__ vf,
    const u16* __restrict__ mn, const u16* __restrict__ wmg,
    const u16* __restrict__ wof, float* __restrict__ out) {
  __shared__ __attribute__((aligned(16))) u16 ring[5][6144];  // A 8KB | B 4KB
  __shared__ __attribute__((aligned(16))) u16 sbnc[4][64 * 36];  // per-wave bounce
  const int tid = threadIdx.x, lane = tid & 63, wv = tid >> 6;
  const int q = (lane >> 4) & 3;
  const int wr = wv >> 1, wc = wv & 1;
  const int bid = blockIdx.x;            // 0..511
  const int xcd = bid & 7, j = bid >> 3; // j 0..63
  const int xt = xcd * 16 + (j >> 2);    // np-tile 0..127 (partitioned by XCD)
  const int yt = j & 3;                  // i-tile 0..3 (consecutive per panel)
  const int i0 = yt * 128;
  const int n0 = xt * 64;
  const int s  = xt * 2 + wc;

  // staging offsets (per wave): A 2KB (2 loads), B 1KB (1 load)
  const int sbA0 = wv * 2048, sbA1 = wv * 2048 + 1024, sbB = wv * 1024;
  const int soA0 = swz(sbA0 + lane * 16);
  const int soA1 = swz(sbA1 + lane * 16);
  const int soB  = swz(sbB + lane * 16);

  // LDS read offsets
  int offA[4], offB[2];
  #pragma unroll
  for (int f = 0; f < 4; ++f)
    offA[f] = swz((wr * 64 + f * 16 + (lane & 15)) * 64 + q * 16);
  #pragma unroll
  for (int f = 0; f < 2; ++f)
    offB[f] = 8192 + swz((wc * 32 + f * 16 + (lane & 15)) * 64 + q * 16);

  f32x4 acc[4][2];   // o fragments: [fi][fn]; col=lane&15 -> i, row -> k
  f32x4 oacc[4][4];  // out fragments: [cn][fi]; col -> i, row -> c
  #pragma unroll
  for (int a = 0; a < 4; ++a) {
    #pragma unroll
    for (int b = 0; b < 2; ++b) acc[a][b] = (f32x4){0.f, 0.f, 0.f, 0.f};
    #pragma unroll
    for (int b = 0; b < 4; ++b) oacc[a][b] = (f32x4){0.f, 0.f, 0.f, 0.f};
  }

#define STAGE(tt, slot)                                                    \
  do {                                                                     \
    const char* pA_ = (const char*)(wf + ((size_t)(tt) * 512 + i0) * 32);  \
    const char* pB_ = (const char*)(vf + ((size_t)(tt) * 8192 + n0) * 32); \
    char* dA_ = (char*)&ring[(slot)][0];                                   \
    char* dB_ = (char*)&ring[(slot)][4096];                                \
    gload_lds16(pA_ + soA0, dA_ + sbA0);                                   \
    gload_lds16(pA_ + soA1, dA_ + sbA1);                                   \
    gload_lds16(pB_ + soB,  dB_ + sbB);                                    \
  } while (0)

#define COMPUTE(slot)                                                      \
  do {                                                                     \
    const char* cS_ = (const char*)&ring[(slot)][0];                       \
    bf16x8 af_[4], bf_[2];                                                 \
    _Pragma("unroll")                                                      \
    for (int f = 0; f < 4; ++f) af_[f] = ld8((const u16*)(cS_ + offA[f])); \
    _Pragma("unroll")                                                      \
    for (int f = 0; f < 2; ++f) bf_[f] = ld8((const u16*)(cS_ + offB[f])); \
    _Pragma("unroll")                                                      \
    for (int fi = 0; fi < 4; ++fi)                                         \
      _Pragma("unroll")                                                    \
      for (int fn = 0; fn < 2; ++fn)                                       \
        acc[fi][fn] = mfma16(bf_[fn], af_[fi], acc[fi][fn]);               \
  } while (0)

  // per-head interlude: gate o with sigmoid(mn@Wg_h), bounce, project into oacc
#define INTERLUDE(hh)                                                      \
  do {                                                                     \
    bf16x8 wg_[2][2], mnf_[4][2];                                          \
    _Pragma("unroll")                                                      \
    for (int k2 = 0; k2 < 2; ++k2)                                         \
      _Pragma("unroll")                                                    \
      for (int kk = 0; kk < 2; ++kk)                                       \
        wg_[k2][kk] = ld8(wmg + ((16 + (hh) * 2 + k2) * 2 + kk) * 512 + lane * 8); \
    _Pragma("unroll")                                                      \
    for (int fi = 0; fi < 4; ++fi) {                                       \
      const u16* mp_ = mn + (size_t)(s * N_DIM + i0 + wr * 64 + fi * 16    \
                                     + (lane & 15)) * DM + q * 8;          \
      mnf_[fi][0] = ld8(mp_);                                              \
      mnf_[fi][1] = ld8(mp_ + 32);                                         \
    }                                                                      \
    u16* bb_ = &sbnc[wv][0];                                               \
    _Pragma("unroll")                                                      \
    for (int fi = 0; fi < 4; ++fi) {                                       \
      _Pragma("unroll")                                                    \
      for (int fn = 0; fn < 2; ++fn) {                                     \
        f32x4 ga_ = (f32x4){0.f, 0.f, 0.f, 0.f};                           \
        ga_ = mfma16(wg_[fn][0], mnf_[fi][0], ga_);                        \
        ga_ = mfma16(wg_[fn][1], mnf_[fi][1], ga_);                        \
        ushort4 pk_;                                                       \
        pk_.x = f2bf(acc[fi][fn][0] / (1.f + __expf(-ga_[0])));            \
        pk_.y = f2bf(acc[fi][fn][1] / (1.f + __expf(-ga_[1])));            \
        pk_.z = f2bf(acc[fi][fn][2] / (1.f + __expf(-ga_[2])));            \
        pk_.w = f2bf(acc[fi][fn][3] / (1.f + __expf(-ga_[3])));            \
        *(ushort4*)(bb_ + (fi * 16 + (lane & 15)) * 36 + fn * 16 + q * 4) = pk_; \
        acc[fi][fn] = (f32x4){0.f, 0.f, 0.f, 0.f};                         \
      }                                                                    \
    }                                                                      \
    asm volatile("s_waitcnt lgkmcnt(0)" ::: "memory");                     \
    __builtin_amdgcn_sched_barrier(0);                                     \
    bf16x8 ogf_[4], wo_[4];                                                \
    _Pragma("unroll")                                                      \
    for (int fi = 0; fi < 4; ++fi)                                         \
      ogf_[fi] = ld8(bb_ + (fi * 16 + (lane & 15)) * 36 + q * 8);          \
    _Pragma("unroll")                                                      \
    for (int cn = 0; cn < 4; ++cn)                                         \
      wo_[cn] = ld8(wof + ((cn * 8 + (hh)) * 64 + lane) * 8);              \
    _Pragma("unroll")                                                      \
    for (int cn = 0; cn < 4; ++cn)                                         \
      _Pragma("unroll")                                                    \
      for (int fi = 0; fi < 4; ++fi)                                       \
        oacc[cn][fi] = mfma16(wo_[cn], ogf_[fi], oacc[cn][fi]);            \
  } while (0)

  // prologue: tiles 0..3 in flight (t enumerates (h,jt) = t>>4, t&15)
  STAGE(0, 0);
  STAGE(1, 1);
  STAGE(2, 2);
  STAGE(3, 3);
  for (int t = 0; t < 125; ++t) {
    asm volatile("s_waitcnt vmcnt(9)" ::: "memory");  // tile t landed; t+1..t+3 in flight
    BARRIER();
    if (t < 124) STAGE(t + 4, (t + 4) % 5);
    COMPUTE(t % 5);
    if ((t & 15) == 15) INTERLUDE(t >> 4);  // heads 0..6
  }
  asm volatile("s_waitcnt vmcnt(6)" ::: "memory");
  BARRIER();
  COMPUTE(125 % 5);
  asm volatile("s_waitcnt vmcnt(3)" ::: "memory");
  BARRIER();
  COMPUTE(126 % 5);
  asm volatile("s_waitcnt vmcnt(0)" ::: "memory");
  BARRIER();
  COMPUTE(127 % 5);
  INTERLUDE(7);
#undef STAGE
#undef COMPUTE
#undef INTERLUDE

  // epilogue: write out[s][i][c] f32 (col=lane&15 -> i, row q*4+rg -> c)
  #pragma unroll
  for (int cn = 0; cn < 4; ++cn) {
    #pragma unroll
    for (int fi = 0; fi < 4; ++fi) {
      float* op = out + (size_t)(s * N_DIM + i0 + wr * 64 + fi * 16
                                 + (lane & 15)) * DM + cn * 16 + q * 4;
      *(f32x4*)op = oacc[cn][fi];
    }
  }
}

extern "C" void kernel_launch(void* const* d_in, const int* in_sizes, int n_in,
                              void* d_out, int out_size, void* d_ws, size_t ws_size,
                              hipStream_t stream) {
  const float* m   = (const float*)d_in[0];
  const float* z   = (const float*)d_in[1];
  const float* mnw = (const float*)d_in[2];
  const float* mnb = (const float*)d_in[3];
  const float* znw = (const float*)d_in[4];
  const float* znb = (const float*)d_in[5];
  const float* Wm  = (const float*)d_in[6];
  const float* Wg  = (const float*)d_in[7];
  const float* Wz  = (const float*)d_in[8];
  const float* Wo  = (const float*)d_in[9];
  float* out = (float*)d_out;
  char* ws = (char*)d_ws;

  // ws layout (bytes): wf 4MiB | vf 64MiB | (free 64MiB) | mn 16MiB |
  //                    wmg 64KiB | wof 32KiB | wzf 8KiB | t1c 64B
  // bws (8MiB f32) overlaps mn: k1a writes / k1b reads it BEFORE k2a writes mn.
  u16*   wbuf = (u16*)(ws);
  u16*   vf   = (u16*)(ws + ((size_t)4   << 20));
  u16*   mn   = (u16*)(ws + ((size_t)132 << 20));
  float* bws  = (float*)(ws + ((size_t)132 << 20));
  u16*   wmg  = (u16*)(ws + ((size_t)148 << 20));
  u16*   wof  = (u16*)(ws + ((size_t)148 << 20) + 65536);
  u16*   wzf  = (u16*)(ws + ((size_t)148 << 20) + 98304);
  float* t1c  = (float*)(ws + ((size_t)148 << 20) + 106496);

  k0_prep<<<209, 256, 0, stream>>>(Wm, Wg, Wo, znw, znb, Wz, wmg, wof, wzf, t1c);
  k1a_bias<<<dim3(8, 512), 256, 0, stream>>>(z, wzf, t1c, bws);
  k1b_softmax<<<1024, 256, 0, stream>>>(bws, wbuf);
  k2a_ln_m<<<512, 256, 0, stream>>>(m, mnw, mnb, mn);
  k2b_proj<<<2048, 256, 0, stream>>>(mn, wmg, vf);
  k3_fused<<<512, 256, 0, stream>>>(wbuf, vf, mn, wmg, wof, out);
}

// Round 10
// 167.920 us; speedup vs baseline: 1.1230x; 1.0528x over previous
//
#include <hip/hip_runtime.h>

// PairWeightedAveraging: m[1,S,N,Dm], z[1,N,N,Dz] -> out[1,S,N,Dm]
// S=256 N=512 Dm=64 Dz=128 H=8 HD=32
// Pipeline (all bf16 MFMA):
//  k0: pre-swizzle [Wm|Wg], Wo, and W'=znw*Wz (split hi/lo bf16) frag tables
//  k1a: bias b[h][i][j] = rs*(z.W'_h - mu*t1[h]) + cst[h] via split-bf16 MFMA
//  k1b: row softmax over j -> wf[h][jt][i][32] bf16 (K-panel layout)
//  k2a: LN(m) -> mn bf16
//  k2b: v = mn @ Wm -> vf[h][jt][np][32]
//  k3_fused: per block (i-tile 64, np-tile 64 = 2 s), loop ALL 8 heads:
//      o_h = w_h @ v_h (3-slot ring, counted vmcnt(2)); at head end:
//      g = sigmoid(mn@Wg_h) pointwise gate; LDS bounce og -> B-frag;
//      out_acc += Wo_h-frag @ og. Writes out once.
//  R9->R10: R7/R9 identical at 108us despite pipeline depth 2 vs 4 ->
//  stall is TLP starvation (2 blk/CU = 2 waves/SIMD), not load latency.
//  Fix: i-tile 128->64, 1024 blocks, LDS 78->33.8KB, launch_bounds(256,4)
//  -> 4 blk/CU = 16 waves/CU = 4 waves/SIMD.

#define S_DIM 256
#define N_DIM 512
#define DM 64
#define DZ 128
#define NH 8
#define HD 32
#define HK 256
#define NP 8192  // S_DIM*HD
#define BKP 32   // K-panel depth
#define JT_N 16  // 512 / BKP

typedef unsigned int   u32;
typedef unsigned short u16;
typedef __bf16 bf16x8 __attribute__((ext_vector_type(8)));
typedef float  f32x4  __attribute__((ext_vector_type(4)));
typedef u32    u32x4  __attribute__((ext_vector_type(4)));

__device__ __forceinline__ u16 f2bf(float f) {
  u32 u = __builtin_bit_cast(u32, f);
  return (u16)((u + 0x7FFFu + ((u >> 16) & 1u)) >> 16);  // RNE
}
__device__ __forceinline__ float bf2f(u16 h) {
  u32 u = ((u32)h) << 16;
  return __builtin_bit_cast(float, u);
}
__device__ __forceinline__ u32 pack2(float a, float b) {
  return (u32)f2bf(a) | ((u32)f2bf(b) << 16);
}
__device__ __forceinline__ bf16x8 ld8(const u16* p) {
  return __builtin_bit_cast(bf16x8, *(const u32x4*)p);
}
__device__ __forceinline__ f32x4 mfma16(bf16x8 a, bf16x8 b, f32x4 c) {
  return __builtin_amdgcn_mfma_f32_16x16x32_bf16(a, b, c, 0, 0, 0);
}
__device__ __forceinline__ void gload_lds16(const void* gsrc, void* ldst) {
  __builtin_amdgcn_global_load_lds(
      (const __attribute__((address_space(1))) void*)gsrc,
      (__attribute__((address_space(3))) void*)ldst, 16, 0, 0);
}
// panel byte-offset swizzle (involution; permutes 16B chunks within 8 rows of 64B)
__device__ __forceinline__ int swz(int lin) { return lin ^ (((lin >> 7) & 3) << 4); }

#define BARRIER() do { asm volatile("" ::: "memory"); \
                       __builtin_amdgcn_s_barrier();  \
                       asm volatile("" ::: "memory"); } while (0)

// ---------------- k0: weight fragment tables ----------------
// wmg: [cb(32)][ks(2)][lane(64)][t(8)]  c=cb*16+(lane&15), k=ks*32+(lane>>4)*8+t
// wof: [cb(4)][ks(8)][lane(64)][t(8)]   c=cb*16+(lane&15), hk=ks*32+(lane>>4)*8+t
// wzf: [ks(4)][p(2)][lane(64)][t(8)]    h=lane&15 (<8), k=ks*32+(lane>>4)*8+t
// t1c: [0..7]=t1[h]=sum_c W'[c][h]; [8..15]=cst[h]=sum_c znb[c]*Wz[c][h]
__global__ __launch_bounds__(256) void k0_prep(
    const float* __restrict__ Wm, const float* __restrict__ Wg,
    const float* __restrict__ Wo, const float* __restrict__ znw,
    const float* __restrict__ znb, const float* __restrict__ Wz,
    u16* __restrict__ wmg, u16* __restrict__ wof,
    u16* __restrict__ wzf, float* __restrict__ t1c) {
  const int idx = blockIdx.x * 256 + threadIdx.x;
  if (idx < 32768) {
    const int t = idx & 7, lane = (idx >> 3) & 63, ks = (idx >> 9) & 1, cb = idx >> 10;
    const int c = cb * 16 + (lane & 15);
    const int k = ks * 32 + ((lane >> 4) & 3) * 8 + t;
    const float v = (c < HK) ? Wm[k * HK + c] : Wg[k * HK + (c - HK)];
    wmg[idx] = f2bf(v);
  } else if (idx < 32768 + 16384) {
    const int j = idx - 32768;
    const int t = j & 7, lane = (j >> 3) & 63, ks = (j >> 9) & 7, cb = j >> 12;
    const int c = cb * 16 + (lane & 15);
    const int hk = ks * 32 + ((lane >> 4) & 3) * 8 + t;
    wof[j] = f2bf(Wo[hk * DM + c]);
  } else if (idx < 49152 + 4096) {
    const int q = idx - 49152;
    const int t = q & 7, lane = (q >> 3) & 63, p = (q >> 9) & 1, ks = q >> 10;
    const int h = lane & 15;
    const int k = ks * 32 + ((lane >> 4) & 3) * 8 + t;
    u16 val = 0;
    if (h < NH) {
      const float wp = znw[k] * Wz[k * NH + h];
      const u16 hi = f2bf(wp);
      val = (p == 0) ? hi : f2bf(wp - bf2f(hi));
    }
    wzf[q] = val;
  } else if (idx < 49152 + 4096 + 16) {
    const int q = idx - 49152 - 4096;  // 0..15
    const int h = q & 7;
    float s = 0.f;
    for (int c = 0; c < DZ; ++c)
      s += ((q < 8) ? znw[c] : znb[c]) * Wz[c * NH + h];
    t1c[q] = s;
  }
}

// ---------------- k1a: bias via split-bf16 MFMA ----------------
__global__ __launch_bounds__(256) void k1a_bias(
    const float* __restrict__ z, const u16* __restrict__ wzf,
    const float* __restrict__ t1c, float* __restrict__ bws) {
  __shared__ float sB[NH][72];
  const int tid = threadIdx.x, lane = tid & 63, wv = tid >> 6;
  const int jb = blockIdx.x, i = blockIdx.y;
  const int jrow = jb * 64 + wv * 16 + (lane & 15);
  const float* zp = z + ((size_t)i * N_DIM + jrow) * DZ + ((lane >> 4) & 3) * 8;
  f32x4 acc = (f32x4){0.f, 0.f, 0.f, 0.f};
  float sum = 0.f, sq = 0.f;
  #pragma unroll
  for (int ks = 0; ks < 4; ++ks) {
    const float4 v0 = *(const float4*)(zp + ks * 32);
    const float4 v1 = *(const float4*)(zp + ks * 32 + 4);
    const float xs[8] = {v0.x, v0.y, v0.z, v0.w, v1.x, v1.y, v1.z, v1.w};
    bf16x8 zh, zl;
    #pragma unroll
    for (int t = 0; t < 8; ++t) {
      sum += xs[t]; sq += xs[t] * xs[t];
      const u16 h16 = f2bf(xs[t]);
      ((u16*)&zh)[t] = h16;
      ((u16*)&zl)[t] = f2bf(xs[t] - bf2f(h16));
    }
    const bf16x8 wh = ld8(wzf + (ks * 2 + 0) * 512 + lane * 8);
    const bf16x8 wl = ld8(wzf + (ks * 2 + 1) * 512 + lane * 8);
    acc = mfma16(zh, wh, acc);
    acc = mfma16(zl, wh, acc);
    acc = mfma16(zh, wl, acc);
  }
  sum += __shfl_xor(sum, 16, 64); sum += __shfl_xor(sum, 32, 64);
  sq  += __shfl_xor(sq, 16, 64);  sq  += __shfl_xor(sq, 32, 64);
  const float mu = sum * (1.f / DZ);
  const float rs = rsqrtf(sq * (1.f / DZ) - mu * mu + 1e-5f);
  const int h = lane & 15;
  const float t1 = t1c[h & 7], cst = t1c[8 + (h & 7)];
  #pragma unroll
  for (int rg = 0; rg < 4; ++rg) {
    const int r = ((lane >> 4) & 3) * 4 + rg;
    const float mur = __shfl(mu, r, 64);
    const float rsr = __shfl(rs, r, 64);
    const float bv = rsr * (acc[rg] - mur * t1) + cst;
    if (h < NH) sB[h][wv * 16 + r] = bv;
  }
  __syncthreads();
  #pragma unroll
  for (int q = 0; q < 2; ++q) {
    const int idx = tid + q * 256;
    const int hh = idx >> 6, jl = idx & 63;
    bws[((size_t)hh * N_DIM + i) * N_DIM + jb * 64 + jl] = sB[hh][jl];
  }
}

// ---------------- k1b: row softmax -> wf bf16 K-panel layout ----------------
__global__ __launch_bounds__(256) void k1b_softmax(
    const float* __restrict__ bws, u16* __restrict__ wout) {
  const int tid = threadIdx.x, lane = tid & 63, wv = tid >> 6;
  const int row = blockIdx.x * 4 + wv;  // row = h*512 + i
  const int h = row >> 9, i = row & 511;
  const float* bp = bws + (size_t)row * N_DIM + lane * 8;
  const float4 v0 = *(const float4*)bp;
  const float4 v1 = *(const float4*)(bp + 4);
  float xs[8] = {v0.x, v0.y, v0.z, v0.w, v1.x, v1.y, v1.z, v1.w};
  float mx = xs[0];
  #pragma unroll
  for (int t = 1; t < 8; ++t) mx = fmaxf(mx, xs[t]);
  #pragma unroll
  for (int off = 32; off; off >>= 1) mx = fmaxf(mx, __shfl_xor(mx, off, 64));
  float sm = 0.f;
  #pragma unroll
  for (int t = 0; t < 8; ++t) { xs[t] = __expf(xs[t] - mx); sm += xs[t]; }
  #pragma unroll
  for (int off = 32; off; off >>= 1) sm += __shfl_xor(sm, off, 64);
  const float inv = 1.f / sm;
  u32x4 pk;
  pk[0] = pack2(xs[0] * inv, xs[1] * inv);
  pk[1] = pack2(xs[2] * inv, xs[3] * inv);
  pk[2] = pack2(xs[4] * inv, xs[5] * inv);
  pk[3] = pack2(xs[6] * inv, xs[7] * inv);
  *(u32x4*)(wout + (((size_t)(h * JT_N + (lane >> 2)) * N_DIM + i) << 5)
            + (lane & 3) * 8) = pk;
}

// ---------------- k2a: LN(m) -> mn bf16 [r=(s,n)][64] ----------------
__global__ __launch_bounds__(256) void k2a_ln_m(
    const float* __restrict__ m, const float* __restrict__ mnw,
    const float* __restrict__ mnb, u16* __restrict__ mn) {
  __shared__ float sw[DM], sb[DM];
  const int tid = threadIdx.x;
  if (tid < DM) { sw[tid] = mnw[tid]; sb[tid] = mnb[tid]; }
  __syncthreads();
  const size_t r = (size_t)blockIdx.x * 256 + tid;
  const float4* mp = (const float4*)(m + r * DM);
  float4 arr[16];
  float sum = 0.f, sq = 0.f;
  #pragma unroll
  for (int q = 0; q < 16; ++q) {
    float4 v = mp[q]; arr[q] = v;
    sum += v.x + v.y + v.z + v.w;
    sq  += v.x * v.x + v.y * v.y + v.z * v.z + v.w * v.w;
  }
  const float mu = sum * (1.f / DM);
  const float rs = rsqrtf(sq * (1.f / DM) - mu * mu + 1e-5f);
  uint4* op = (uint4*)(mn + r * DM);
  #pragma unroll
  for (int q = 0; q < 8; ++q) {
    const float4 a = arr[2 * q], b = arr[2 * q + 1];
    const int c0 = q * 8;
    const float y0 = (a.x - mu) * rs * sw[c0 + 0] + sb[c0 + 0];
    const float y1 = (a.y - mu) * rs * sw[c0 + 1] + sb[c0 + 1];
    const float y2 = (a.z - mu) * rs * sw[c0 + 2] + sb[c0 + 2];
    const float y3 = (a.w - mu) * rs * sw[c0 + 3] + sb[c0 + 3];
    const float y4 = (b.x - mu) * rs * sw[c0 + 4] + sb[c0 + 4];
    const float y5 = (b.y - mu) * rs * sw[c0 + 5] + sb[c0 + 5];
    const float y6 = (b.z - mu) * rs * sw[c0 + 6] + sb[c0 + 6];
    const float y7 = (b.w - mu) * rs * sw[c0 + 7] + sb[c0 + 7];
    uint4 u;
    u.x = pack2(y0, y1); u.y = pack2(y2, y3);
    u.z = pack2(y4, y5); u.w = pack2(y6, y7);
    op[q] = u;
  }
}

// ---------------- k2b: v = mn @ Wm -> vf[h][jt][np][32] ----------------
__global__ __launch_bounds__(256) void k2b_proj(
    const u16* __restrict__ mn, const u16* __restrict__ wmg,
    u16* __restrict__ vf) {
  const int tid = threadIdx.x, lane = tid & 63, wv = tid >> 6;
  const int rbase = (blockIdx.x * 4 + wv) * 16;
  const u16* ap = mn + (size_t)(rbase + (lane & 15)) * DM + ((lane >> 4) & 3) * 8;
  const bf16x8 a0 = ld8(ap);
  const bf16x8 a1 = ld8(ap + 32);
  const u16* bp = wmg + lane * 8;
  const int r0 = rbase + ((lane >> 4) & 3) * 4;
  const int s0 = r0 >> 9;
  const int j0 = r0 & 511;

  f32x4 acc[16];
  #pragma unroll
  for (int cb = 0; cb < 16; ++cb) acc[cb] = (f32x4){0.f, 0.f, 0.f, 0.f};
  #pragma unroll
  for (int cb = 0; cb < 16; ++cb) {
    acc[cb] = mfma16(a0, ld8(bp + cb * 1024), acc[cb]);
    acc[cb] = mfma16(a1, ld8(bp + cb * 1024 + 512), acc[cb]);
  }
  #pragma unroll
  for (int cb = 0; cb < 16; ++cb) {
    const int c = cb * 16 + (lane & 15);
    const int h = c >> 5, k = c & 31;
    const int np = s0 * HD + k;
    const size_t idx = (((size_t)(h * JT_N + (j0 >> 5)) * NP + np) << 5) + (j0 & 31);
    ushort4 pk;
    pk.x = f2bf(acc[cb][0]); pk.y = f2bf(acc[cb][1]);
    pk.z = f2bf(acc[cb][2]); pk.w = f2bf(acc[cb][3]);
    *(ushort4*)(vf + idx) = pk;
  }
}

// ---------------- k3_fused: o = w@v over all heads + gate + Wo projection ----
// Block: i-tile 64 (yt), np-tile 64 = 2 s (xt). 4 waves: (wr: i-half 32, wc: s).
// XCD map: xcd = bid&7 owns np-tiles [xcd*16,(xcd+1)*16); the 8 i-tiles
// sharing each vf panel are consecutive on one XCD.
// 3-slot ring (A 4KB | B 4KB per slot), in-loop wait vmcnt(2).
// LDS 33.8KB -> 4 blocks/CU = 16 waves/CU = 4 waves/SIMD.
__global__ __launch_bounds__(256, 4) void k3_fused(
    const u16* __restrict__ wf, const u16* __restrict__ vf,
    const u16* __restrict__ mn, const u16* __restrict__ wmg,
    const u16* __restrict__ wof, float* __restrict__ out) {
  __shared__ __attribute__((aligned(16))) u16 ring[3][4096];  // A 4KB | B 4KB
  __shared__ __attribute__((aligned(16))) u16 sbnc[4][32 * 36];  // per-wave bounce
  const int tid = threadIdx.x, lane = tid & 63, wv = tid >> 6;
  const int q = (lane >> 4) & 3;
  const int wr = wv >> 1, wc = wv & 1;
  const int bid = blockIdx.x;            // 0..1023
  const int xcd = bid & 7, j = bid >> 3; // j 0..127
  const int xt = xcd * 16 + (j >> 3);    // np-tile 0..127 (partitioned by XCD)
  const int yt = j & 7;                  // i-tile 0..7 (consecutive per panel)
  const int i0 = yt * 64;
  const int n0 = xt * 64;
  const int s  = xt * 2 + wc;

  // staging offsets (per wave): A 1KB (1 load), B 1KB (1 load)
  const int sbA = wv * 1024;
  const int sbB = wv * 1024;  // within B region (slot byte 4096+)
  const int soA = swz(sbA + lane * 16);
  const int soB = swz(sbB + lane * 16);

  // LDS read offsets (bytes within slot; B region at +4096)
  int offA[2], offB[2];
  #pragma unroll
  for (int f = 0; f < 2; ++f)
    offA[f] = swz((wr * 32 + f * 16 + (lane & 15)) * 64 + q * 16);
  #pragma unroll
  for (int f = 0; f < 2; ++f)
    offB[f] = 4096 + swz((wc * 32 + f * 16 + (lane & 15)) * 64 + q * 16);

  f32x4 acc[2][2];   // o fragments: [fi][fn]; col=lane&15 -> i, row -> k
  f32x4 oacc[4][2];  // out fragments: [cn][fi]; col -> i, row -> c
  #pragma unroll
  for (int a = 0; a < 2; ++a)
    #pragma unroll
    for (int b = 0; b < 2; ++b) acc[a][b] = (f32x4){0.f, 0.f, 0.f, 0.f};
  #pragma unroll
  for (int a = 0; a < 4; ++a)
    #pragma unroll
    for (int b = 0; b < 2; ++b) oacc[a][b] = (f32x4){0.f, 0.f, 0.f, 0.f};

#define STAGE(tt, slot)                                                    \
  do {                                                                     \
    const char* pA_ = (const char*)(wf + ((size_t)(tt) * 512 + i0) * 32);  \
    const char* pB_ = (const char*)(vf + ((size_t)(tt) * 8192 + n0) * 32); \
    char* dA_ = (char*)&ring[(slot)][0];                                   \
    char* dB_ = dA_ + 4096;                                                \
    gload_lds16(pA_ + soA, dA_ + sbA);                                     \
    gload_lds16(pB_ + soB, dB_ + sbB);                                     \
  } while (0)

#define COMPUTE(slot)                                                      \
  do {                                                                     \
    const char* cS_ = (const char*)&ring[(slot)][0];                       \
    bf16x8 af_[2], bf_[2];                                                 \
    _Pragma("unroll")                                                      \
    for (int f = 0; f < 2; ++f) af_[f] = ld8((const u16*)(cS_ + offA[f])); \
    _Pragma("unroll")                                                      \
    for (int f = 0; f < 2; ++f) bf_[f] = ld8((const u16*)(cS_ + offB[f])); \
    _Pragma("unroll")                                                      \
    for (int fi = 0; fi < 2; ++fi)                                         \
      _Pragma("unroll")                                                    \
      for (int fn = 0; fn < 2; ++fn)                                       \
        acc[fi][fn] = mfma16(bf_[fn], af_[fi], acc[fi][fn]);               \
  } while (0)

  // per-head interlude: gate o with sigmoid(mn@Wg_h), bounce, project into oacc
#define INTERLUDE(hh)                                                      \
  do {                                                                     \
    bf16x8 wg_[2][2], mnf_[2][2];                                          \
    _Pragma("unroll")                                                      \
    for (int k2 = 0; k2 < 2; ++k2)                                         \
      _Pragma("unroll")                                                    \
      for (int kk = 0; kk < 2; ++kk)                                       \
        wg_[k2][kk] = ld8(wmg + ((16 + (hh) * 2 + k2) * 2 + kk) * 512 + lane * 8); \
    _Pragma("unroll")                                                      \
    for (int fi = 0; fi < 2; ++fi) {                                       \
      const u16* mp_ = mn + (size_t)(s * N_DIM + i0 + wr * 32 + fi * 16    \
                                     + (lane & 15)) * DM + q * 8;          \
      mnf_[fi][0] = ld8(mp_);                                              \
      mnf_[fi][1] = ld8(mp_ + 32);                                         \
    }                                                                      \
    u16* bb_ = &sbnc[wv][0];                                               \
    _Pragma("unroll")                                                      \
    for (int fi = 0; fi < 2; ++fi) {                                       \
      _Pragma("unroll")                                                    \
      for (int fn = 0; fn < 2; ++fn) {                                     \
        f32x4 ga_ = (f32x4){0.f, 0.f, 0.f, 0.f};                           \
        ga_ = mfma16(wg_[fn][0], mnf_[fi][0], ga_);                        \
        ga_ = mfma16(wg_[fn][1], mnf_[fi][1], ga_);                        \
        ushort4 pk_;                                                       \
        pk_.x = f2bf(acc[fi][fn][0] / (1.f + __expf(-ga_[0])));            \
        pk_.y = f2bf(acc[fi][fn][1] / (1.f + __expf(-ga_[1])));            \
        pk_.z = f2bf(acc[fi][fn][2] / (1.f + __expf(-ga_[2])));            \
        pk_.w = f2bf(acc[fi][fn][3] / (1.f + __expf(-ga_[3])));            \
        *(ushort4*)(bb_ + (fi * 16 + (lane & 15)) * 36 + fn * 16 + q * 4) = pk_; \
        acc[fi][fn] = (f32x4){0.f, 0.f, 0.f, 0.f};                         \
      }                                                                    \
    }                                                                      \
    asm volatile("s_waitcnt lgkmcnt(0)" ::: "memory");                     \
    __builtin_amdgcn_sched_barrier(0);                                     \
    bf16x8 ogf_[2], wo_[4];                                                \
    _Pragma("unroll")                                                      \
    for (int fi = 0; fi < 2; ++fi)                                         \
      ogf_[fi] = ld8(bb_ + (fi * 16 + (lane & 15)) * 36 + q * 8);          \
    _Pragma("unroll")                                                      \
    for (int cn = 0; cn < 4; ++cn)                                         \
      wo_[cn] = ld8(wof + ((cn * 8 + (hh)) * 64 + lane) * 8);              \
    _Pragma("unroll")                                                      \
    for (int cn = 0; cn < 4; ++cn)                                         \
      _Pragma("unroll")                                                    \
      for (int fi = 0; fi < 2; ++fi)                                       \
        oacc[cn][fi] = mfma16(wo_[cn], ogf_[fi], oacc[cn][fi]);            \
  } while (0)

  // prologue: tiles 0,1 in flight (t enumerates (h,jt) = t>>4, t&15)
  STAGE(0, 0);
  STAGE(1, 1);
  for (int t = 0; t < 126; ++t) {
    asm volatile("s_waitcnt vmcnt(2)" ::: "memory");  // tile t landed; t+1 in flight
    BARRIER();
    STAGE(t + 2, (t + 2) % 3);
    COMPUTE(t % 3);
    if ((t & 15) == 15) INTERLUDE(t >> 4);  // heads 0..6
  }
  asm volatile("s_waitcnt vmcnt(2)" ::: "memory");
  BARRIER();
  COMPUTE(126 % 3);
  asm volatile("s_waitcnt vmcnt(0)" ::: "memory");
  BARRIER();
  COMPUTE(127 % 3);
  INTERLUDE(7);
#undef STAGE
#undef COMPUTE
#undef INTERLUDE

  // epilogue: write out[s][i][c] f32 (col=lane&15 -> i, row q*4+rg -> c)
  #pragma unroll
  for (int cn = 0; cn < 4; ++cn) {
    #pragma unroll
    for (int fi = 0; fi < 2; ++fi) {
      float* op = out + (size_t)(s * N_DIM + i0 + wr * 32 + fi * 16
                                 + (lane & 15)) * DM + cn * 16 + q * 4;
      *(f32x4*)op = oacc[cn][fi];
    }
  }
}

extern "C" void kernel_launch(void* const* d_in, const int* in_sizes, int n_in,
                              void* d_out, int out_size, void* d_ws, size_t ws_size,
                              hipStream_t stream) {
  const float* m   = (const float*)d_in[0];
  const float* z   = (const float*)d_in[1];
  const float* mnw = (const float*)d_in[2];
  const float* mnb = (const float*)d_in[3];
  const float* znw = (const float*)d_in[4];
  const float* znb = (const float*)d_in[5];
  const float* Wm  = (const float*)d_in[6];
  const float* Wg  = (const float*)d_in[7];
  const float* Wz  = (const float*)d_in[8];
  const float* Wo  = (const float*)d_in[9];
  float* out = (float*)d_out;
  char* ws = (char*)d_ws;

  // ws layout (bytes): wf 4MiB | vf 64MiB | (free 64MiB) | mn 16MiB |
  //                    wmg 64KiB | wof 32KiB | wzf 8KiB | t1c 64B
  // bws (8MiB f32) overlaps mn: k1a writes / k1b reads it BEFORE k2a writes mn.
  u16*   wbuf = (u16*)(ws);
  u16*   vf   = (u16*)(ws + ((size_t)4   << 20));
  u16*   mn   = (u16*)(ws + ((size_t)132 << 20));
  float* bws  = (float*)(ws + ((size_t)132 << 20));
  u16*   wmg  = (u16*)(ws + ((size_t)148 << 20));
  u16*   wof  = (u16*)(ws + ((size_t)148 << 20) + 65536);
  u16*   wzf  = (u16*)(ws + ((size_t)148 << 20) + 98304);
  float* t1c  = (float*)(ws + ((size_t)148 << 20) + 106496);

  k0_prep<<<209, 256, 0, stream>>>(Wm, Wg, Wo, znw, znb, Wz, wmg, wof, wzf, t1c);
  k1a_bias<<<dim3(8, 512), 256, 0, stream>>>(z, wzf, t1c, bws);
  k1b_softmax<<<1024, 256, 0, stream>>>(bws, wbuf);
  k2a_ln_m<<<512, 256, 0, stream>>>(m, mnw, mnb, mn);
  k2b_proj<<<2048, 256, 0, stream>>>(mn, wmg, vf);
  k3_fused<<<1024, 256, 0, stream>>>(wbuf, vf, mn, wmg, wof, out);
}

// Round 11
// 139.517 us; speedup vs baseline: 1.3516x; 1.2036x over previous
//
#include <hip/hip_runtime.h>

// PairWeightedAveraging: m[1,S,N,Dm], z[1,N,N,Dz] -> out[1,S,N,Dm]
// S=256 N=512 Dm=64 Dz=128 H=8 HD=32
// Pipeline (all bf16 MFMA):
//  k0: pre-swizzle [Wm|Wg], Wo, and W'=znw*Wz (split hi/lo bf16) frag tables
//  k1a: bias b[h][i][j] = rs*(z.W'_h - mu*t1[h]) + cst[h] via split-bf16 MFMA
//  k1b: row softmax over j -> wf[h][jt][i][32] bf16 (K-panel layout)
//  k2a: LN(m) -> mn bf16
//  k2b: v = mn @ Wm -> vf[h][jt][np][32]
//  k3_fused: per block (i-tile 64, np-tile 64 = 2 s), loop ALL 8 heads.
//  R10->R11 (same math, body cleanup): 4-slot ring w/ STATIC slot indices
//  (head-outer loop, 16x unrolled inner), interlude bounce reuses ring slot 2
//  (free at interlude points; LDS = 32KB exact), mn frags hoisted to regs,
//  v_rcp_f32 sigmoid, s_setprio around MFMA cluster.

#define S_DIM 256
#define N_DIM 512
#define DM 64
#define DZ 128
#define NH 8
#define HD 32
#define HK 256
#define NP 8192  // S_DIM*HD
#define BKP 32   // K-panel depth
#define JT_N 16  // 512 / BKP

typedef unsigned int   u32;
typedef unsigned short u16;
typedef __bf16 bf16x8 __attribute__((ext_vector_type(8)));
typedef float  f32x4  __attribute__((ext_vector_type(4)));
typedef u32    u32x4  __attribute__((ext_vector_type(4)));

__device__ __forceinline__ u16 f2bf(float f) {
  u32 u = __builtin_bit_cast(u32, f);
  return (u16)((u + 0x7FFFu + ((u >> 16) & 1u)) >> 16);  // RNE
}
__device__ __forceinline__ float bf2f(u16 h) {
  u32 u = ((u32)h) << 16;
  return __builtin_bit_cast(float, u);
}
__device__ __forceinline__ u32 pack2(float a, float b) {
  return (u32)f2bf(a) | ((u32)f2bf(b) << 16);
}
__device__ __forceinline__ bf16x8 ld8(const u16* p) {
  return __builtin_bit_cast(bf16x8, *(const u32x4*)p);
}
__device__ __forceinline__ f32x4 mfma16(bf16x8 a, bf16x8 b, f32x4 c) {
  return __builtin_amdgcn_mfma_f32_16x16x32_bf16(a, b, c, 0, 0, 0);
}
__device__ __forceinline__ void gload_lds16(const void* gsrc, void* ldst) {
  __builtin_amdgcn_global_load_lds(
      (const __attribute__((address_space(1))) void*)gsrc,
      (__attribute__((address_space(3))) void*)ldst, 16, 0, 0);
}
__device__ __forceinline__ float fast_sigmoid(float x) {
  float r;
  asm("v_rcp_f32 %0, %1" : "=v"(r) : "v"(1.f + __expf(-x)));
  return r;
}
// panel byte-offset swizzle (involution; permutes 16B chunks within 8 rows of 64B)
__device__ __forceinline__ int swz(int lin) { return lin ^ (((lin >> 7) & 3) << 4); }

#define BARRIER() do { asm volatile("" ::: "memory"); \
                       __builtin_amdgcn_s_barrier();  \
                       asm volatile("" ::: "memory"); } while (0)

// ---------------- k0: weight fragment tables ----------------
// wmg: [cb(32)][ks(2)][lane(64)][t(8)]  c=cb*16+(lane&15), k=ks*32+(lane>>4)*8+t
// wof: [cb(4)][ks(8)][lane(64)][t(8)]   c=cb*16+(lane&15), hk=ks*32+(lane>>4)*8+t
// wzf: [ks(4)][p(2)][lane(64)][t(8)]    h=lane&15 (<8), k=ks*32+(lane>>4)*8+t
// t1c: [0..7]=t1[h]=sum_c W'[c][h]; [8..15]=cst[h]=sum_c znb[c]*Wz[c][h]
__global__ __launch_bounds__(256) void k0_prep(
    const float* __restrict__ Wm, const float* __restrict__ Wg,
    const float* __restrict__ Wo, const float* __restrict__ znw,
    const float* __restrict__ znb, const float* __restrict__ Wz,
    u16* __restrict__ wmg, u16* __restrict__ wof,
    u16* __restrict__ wzf, float* __restrict__ t1c) {
  const int idx = blockIdx.x * 256 + threadIdx.x;
  if (idx < 32768) {
    const int t = idx & 7, lane = (idx >> 3) & 63, ks = (idx >> 9) & 1, cb = idx >> 10;
    const int c = cb * 16 + (lane & 15);
    const int k = ks * 32 + ((lane >> 4) & 3) * 8 + t;
    const float v = (c < HK) ? Wm[k * HK + c] : Wg[k * HK + (c - HK)];
    wmg[idx] = f2bf(v);
  } else if (idx < 32768 + 16384) {
    const int j = idx - 32768;
    const int t = j & 7, lane = (j >> 3) & 63, ks = (j >> 9) & 7, cb = j >> 12;
    const int c = cb * 16 + (lane & 15);
    const int hk = ks * 32 + ((lane >> 4) & 3) * 8 + t;
    wof[j] = f2bf(Wo[hk * DM + c]);
  } else if (idx < 49152 + 4096) {
    const int q = idx - 49152;
    const int t = q & 7, lane = (q >> 3) & 63, p = (q >> 9) & 1, ks = q >> 10;
    const int h = lane & 15;
    const int k = ks * 32 + ((lane >> 4) & 3) * 8 + t;
    u16 val = 0;
    if (h < NH) {
      const float wp = znw[k] * Wz[k * NH + h];
      const u16 hi = f2bf(wp);
      val = (p == 0) ? hi : f2bf(wp - bf2f(hi));
    }
    wzf[q] = val;
  } else if (idx < 49152 + 4096 + 16) {
    const int q = idx - 49152 - 4096;  // 0..15
    const int h = q & 7;
    float s = 0.f;
    for (int c = 0; c < DZ; ++c)
      s += ((q < 8) ? znw[c] : znb[c]) * Wz[c * NH + h];
    t1c[q] = s;
  }
}

// ---------------- k1a: bias via split-bf16 MFMA ----------------
__global__ __launch_bounds__(256) void k1a_bias(
    const float* __restrict__ z, const u16* __restrict__ wzf,
    const float* __restrict__ t1c, float* __restrict__ bws) {
  __shared__ float sB[NH][72];
  const int tid = threadIdx.x, lane = tid & 63, wv = tid >> 6;
  const int jb = blockIdx.x, i = blockIdx.y;
  const int jrow = jb * 64 + wv * 16 + (lane & 15);
  const float* zp = z + ((size_t)i * N_DIM + jrow) * DZ + ((lane >> 4) & 3) * 8;
  f32x4 acc = (f32x4){0.f, 0.f, 0.f, 0.f};
  float sum = 0.f, sq = 0.f;
  #pragma unroll
  for (int ks = 0; ks < 4; ++ks) {
    const float4 v0 = *(const float4*)(zp + ks * 32);
    const float4 v1 = *(const float4*)(zp + ks * 32 + 4);
    const float xs[8] = {v0.x, v0.y, v0.z, v0.w, v1.x, v1.y, v1.z, v1.w};
    bf16x8 zh, zl;
    #pragma unroll
    for (int t = 0; t < 8; ++t) {
      sum += xs[t]; sq += xs[t] * xs[t];
      const u16 h16 = f2bf(xs[t]);
      ((u16*)&zh)[t] = h16;
      ((u16*)&zl)[t] = f2bf(xs[t] - bf2f(h16));
    }
    const bf16x8 wh = ld8(wzf + (ks * 2 + 0) * 512 + lane * 8);
    const bf16x8 wl = ld8(wzf + (ks * 2 + 1) * 512 + lane * 8);
    acc = mfma16(zh, wh, acc);
    acc = mfma16(zl, wh, acc);
    acc = mfma16(zh, wl, acc);
  }
  sum += __shfl_xor(sum, 16, 64); sum += __shfl_xor(sum, 32, 64);
  sq  += __shfl_xor(sq, 16, 64);  sq  += __shfl_xor(sq, 32, 64);
  const float mu = sum * (1.f / DZ);
  const float rs = rsqrtf(sq * (1.f / DZ) - mu * mu + 1e-5f);
  const int h = lane & 15;
  const float t1 = t1c[h & 7], cst = t1c[8 + (h & 7)];
  #pragma unroll
  for (int rg = 0; rg < 4; ++rg) {
    const int r = ((lane >> 4) & 3) * 4 + rg;
    const float mur = __shfl(mu, r, 64);
    const float rsr = __shfl(rs, r, 64);
    const float bv = rsr * (acc[rg] - mur * t1) + cst;
    if (h < NH) sB[h][wv * 16 + r] = bv;
  }
  __syncthreads();
  #pragma unroll
  for (int q = 0; q < 2; ++q) {
    const int idx = tid + q * 256;
    const int hh = idx >> 6, jl = idx & 63;
    bws[((size_t)hh * N_DIM + i) * N_DIM + jb * 64 + jl] = sB[hh][jl];
  }
}

// ---------------- k1b: row softmax -> wf bf16 K-panel layout ----------------
__global__ __launch_bounds__(256) void k1b_softmax(
    const float* __restrict__ bws, u16* __restrict__ wout) {
  const int tid = threadIdx.x, lane = tid & 63, wv = tid >> 6;
  const int row = blockIdx.x * 4 + wv;  // row = h*512 + i
  const int h = row >> 9, i = row & 511;
  const float* bp = bws + (size_t)row * N_DIM + lane * 8;
  const float4 v0 = *(const float4*)bp;
  const float4 v1 = *(const float4*)(bp + 4);
  float xs[8] = {v0.x, v0.y, v0.z, v0.w, v1.x, v1.y, v1.z, v1.w};
  float mx = xs[0];
  #pragma unroll
  for (int t = 1; t < 8; ++t) mx = fmaxf(mx, xs[t]);
  #pragma unroll
  for (int off = 32; off; off >>= 1) mx = fmaxf(mx, __shfl_xor(mx, off, 64));
  float sm = 0.f;
  #pragma unroll
  for (int t = 0; t < 8; ++t) { xs[t] = __expf(xs[t] - mx); sm += xs[t]; }
  #pragma unroll
  for (int off = 32; off; off >>= 1) sm += __shfl_xor(sm, off, 64);
  const float inv = 1.f / sm;
  u32x4 pk;
  pk[0] = pack2(xs[0] * inv, xs[1] * inv);
  pk[1] = pack2(xs[2] * inv, xs[3] * inv);
  pk[2] = pack2(xs[4] * inv, xs[5] * inv);
  pk[3] = pack2(xs[6] * inv, xs[7] * inv);
  *(u32x4*)(wout + (((size_t)(h * JT_N + (lane >> 2)) * N_DIM + i) << 5)
            + (lane & 3) * 8) = pk;
}

// ---------------- k2a: LN(m) -> mn bf16 [r=(s,n)][64] ----------------
__global__ __launch_bounds__(256) void k2a_ln_m(
    const float* __restrict__ m, const float* __restrict__ mnw,
    const float* __restrict__ mnb, u16* __restrict__ mn) {
  __shared__ float sw[DM], sb[DM];
  const int tid = threadIdx.x;
  if (tid < DM) { sw[tid] = mnw[tid]; sb[tid] = mnb[tid]; }
  __syncthreads();
  const size_t r = (size_t)blockIdx.x * 256 + tid;
  const float4* mp = (const float4*)(m + r * DM);
  float4 arr[16];
  float sum = 0.f, sq = 0.f;
  #pragma unroll
  for (int q = 0; q < 16; ++q) {
    float4 v = mp[q]; arr[q] = v;
    sum += v.x + v.y + v.z + v.w;
    sq  += v.x * v.x + v.y * v.y + v.z * v.z + v.w * v.w;
  }
  const float mu = sum * (1.f / DM);
  const float rs = rsqrtf(sq * (1.f / DM) - mu * mu + 1e-5f);
  uint4* op = (uint4*)(mn + r * DM);
  #pragma unroll
  for (int q = 0; q < 8; ++q) {
    const float4 a = arr[2 * q], b = arr[2 * q + 1];
    const int c0 = q * 8;
    const float y0 = (a.x - mu) * rs * sw[c0 + 0] + sb[c0 + 0];
    const float y1 = (a.y - mu) * rs * sw[c0 + 1] + sb[c0 + 1];
    const float y2 = (a.z - mu) * rs * sw[c0 + 2] + sb[c0 + 2];
    const float y3 = (a.w - mu) * rs * sw[c0 + 3] + sb[c0 + 3];
    const float y4 = (b.x - mu) * rs * sw[c0 + 4] + sb[c0 + 4];
    const float y5 = (b.y - mu) * rs * sw[c0 + 5] + sb[c0 + 5];
    const float y6 = (b.z - mu) * rs * sw[c0 + 6] + sb[c0 + 6];
    const float y7 = (b.w - mu) * rs * sw[c0 + 7] + sb[c0 + 7];
    uint4 u;
    u.x = pack2(y0, y1); u.y = pack2(y2, y3);
    u.z = pack2(y4, y5); u.w = pack2(y6, y7);
    op[q] = u;
  }
}

// ---------------- k2b: v = mn @ Wm -> vf[h][jt][np][32] ----------------
__global__ __launch_bounds__(256) void k2b_proj(
    const u16* __restrict__ mn, const u16* __restrict__ wmg,
    u16* __restrict__ vf) {
  const int tid = threadIdx.x, lane = tid & 63, wv = tid >> 6;
  const int rbase = (blockIdx.x * 4 + wv) * 16;
  const u16* ap = mn + (size_t)(rbase + (lane & 15)) * DM + ((lane >> 4) & 3) * 8;
  const bf16x8 a0 = ld8(ap);
  const bf16x8 a1 = ld8(ap + 32);
  const u16* bp = wmg + lane * 8;
  const int r0 = rbase + ((lane >> 4) & 3) * 4;
  const int s0 = r0 >> 9;
  const int j0 = r0 & 511;

  f32x4 acc[16];
  #pragma unroll
  for (int cb = 0; cb < 16; ++cb) acc[cb] = (f32x4){0.f, 0.f, 0.f, 0.f};
  #pragma unroll
  for (int cb = 0; cb < 16; ++cb) {
    acc[cb] = mfma16(a0, ld8(bp + cb * 1024), acc[cb]);
    acc[cb] = mfma16(a1, ld8(bp + cb * 1024 + 512), acc[cb]);
  }
  #pragma unroll
  for (int cb = 0; cb < 16; ++cb) {
    const int c = cb * 16 + (lane & 15);
    const int h = c >> 5, k = c & 31;
    const int np = s0 * HD + k;
    const size_t idx = (((size_t)(h * JT_N + (j0 >> 5)) * NP + np) << 5) + (j0 & 31);
    ushort4 pk;
    pk.x = f2bf(acc[cb][0]); pk.y = f2bf(acc[cb][1]);
    pk.z = f2bf(acc[cb][2]); pk.w = f2bf(acc[cb][3]);
    *(ushort4*)(vf + idx) = pk;
  }
}

// ---------------- k3_fused: o = w@v over all heads + gate + Wo projection ----
// Block: i-tile 64 (yt), np-tile 64 = 2 s (xt). 4 waves: (wr: i-half 32, wc: s).
// XCD map: xcd = bid&7 owns np-tiles [xcd*16,(xcd+1)*16); the 8 i-tiles
// sharing each vf panel are consecutive on one XCD.
// 4-slot ring (A 4KB | B 4KB per slot), STATIC slot indices, vmcnt(2).
// Interlude bounce lives in ring slot 2 (free at every interlude point;
// next write to slot 2 is behind the following barrier). LDS = 32KB exact
// -> 4 blocks/CU.
__global__ __launch_bounds__(256, 4) void k3_fused(
    const u16* __restrict__ wf, const u16* __restrict__ vf,
    const u16* __restrict__ mn, const u16* __restrict__ wmg,
    const u16* __restrict__ wof, float* __restrict__ out) {
  __shared__ __attribute__((aligned(16))) u16 ring[4][4096];  // 8KB/slot: A|B
  const int tid = threadIdx.x, lane = tid & 63, wv = tid >> 6;
  const int q = (lane >> 4) & 3;
  const int wr = wv >> 1, wc = wv & 1;
  const int bid = blockIdx.x;            // 0..1023
  const int xcd = bid & 7, j = bid >> 3; // j 0..127
  const int xt = xcd * 16 + (j >> 3);    // np-tile 0..127 (partitioned by XCD)
  const int yt = j & 7;                  // i-tile 0..7 (consecutive per panel)
  const int i0 = yt * 64;
  const int n0 = xt * 64;
  const int s  = xt * 2 + wc;

  // staging offsets (per wave): A 1KB (1 load), B 1KB (1 load)
  const int sbA = wv * 1024;
  const int soA = swz(sbA + lane * 16);
  const int soB = swz(sbA + lane * 16);  // same per-wave quarter of B panel

  // LDS read offsets (bytes within slot; B region at +4096)
  int offA[2], offB[2];
  #pragma unroll
  for (int f = 0; f < 2; ++f)
    offA[f] = swz((wr * 32 + f * 16 + (lane & 15)) * 64 + q * 16);
  #pragma unroll
  for (int f = 0; f < 2; ++f)
    offB[f] = 4096 + swz((wc * 32 + f * 16 + (lane & 15)) * 64 + q * 16);

  // hoisted mn fragments (head-invariant): rows i0+wr*32+fi*16+(lane&15)
  bf16x8 mnf[2][2];
  #pragma unroll
  for (int fi = 0; fi < 2; ++fi) {
    const u16* mp_ = mn + (size_t)(s * N_DIM + i0 + wr * 32 + fi * 16
                                   + (lane & 15)) * DM + q * 8;
    mnf[fi][0] = ld8(mp_);
    mnf[fi][1] = ld8(mp_ + 32);
  }

  f32x4 acc[2][2];   // o fragments: [fi][fn]; col=lane&15 -> i, row -> k
  f32x4 oacc[4][2];  // out fragments: [cn][fi]; col -> i, row -> c
  #pragma unroll
  for (int a = 0; a < 2; ++a)
    #pragma unroll
    for (int b = 0; b < 2; ++b) acc[a][b] = (f32x4){0.f, 0.f, 0.f, 0.f};
  #pragma unroll
  for (int a = 0; a < 4; ++a)
    #pragma unroll
    for (int b = 0; b < 2; ++b) oacc[a][b] = (f32x4){0.f, 0.f, 0.f, 0.f};

  const char* gA = (const char*)(wf + (size_t)i0 * 32);  // + tile*32768
  const char* gB = (const char*)(vf + (size_t)n0 * 32);  // + tile*524288

#define STAGE_P(pA_, pB_, slot)                                            \
  do {                                                                     \
    char* dA_ = (char*)&ring[(slot)][0];                                   \
    gload_lds16((pA_) + soA, dA_ + sbA);                                   \
    gload_lds16((pB_) + soB, dA_ + 4096 + sbA);                            \
  } while (0)

#define COMPUTE(slot)                                                      \
  do {                                                                     \
    const char* cS_ = (const char*)&ring[(slot)][0];                       \
    bf16x8 af_[2], bf_[2];                                                 \
    _Pragma("unroll")                                                      \
    for (int f = 0; f < 2; ++f) af_[f] = ld8((const u16*)(cS_ + offA[f])); \
    _Pragma("unroll")                                                      \
    for (int f = 0; f < 2; ++f) bf_[f] = ld8((const u16*)(cS_ + offB[f])); \
    __builtin_amdgcn_s_setprio(1);                                         \
    _Pragma("unroll")                                                      \
    for (int fi = 0; fi < 2; ++fi)                                         \
      _Pragma("unroll")                                                    \
      for (int fn = 0; fn < 2; ++fn)                                       \
        acc[fi][fn] = mfma16(bf_[fn], af_[fi], acc[fi][fn]);               \
    __builtin_amdgcn_s_setprio(0);                                         \
  } while (0)

  // per-head interlude: gate o with sigmoid(mn@Wg_h), bounce through ring
  // slot 2 (per-wave 2048B region, [32][32] XOR-swizzled), project into oacc.
#define INTERLUDE(hh)                                                      \
  do {                                                                     \
    bf16x8 wg_[2][2];                                                      \
    _Pragma("unroll")                                                      \
    for (int k2 = 0; k2 < 2; ++k2)                                         \
      _Pragma("unroll")                                                    \
      for (int kk = 0; kk < 2; ++kk)                                       \
        wg_[k2][kk] = ld8(wmg + ((16 + (hh) * 2 + k2) * 2 + kk) * 512 + lane * 8); \
    u16* bb_ = &ring[2][0] + wv * 1024;                                    \
    _Pragma("unroll")                                                      \
    for (int fi = 0; fi < 2; ++fi) {                                       \
      const int row_ = fi * 16 + (lane & 15);                              \
      const int sw_ = (row_ & 3) << 3;                                     \
      _Pragma("unroll")                                                    \
      for (int fn = 0; fn < 2; ++fn) {                                     \
        f32x4 ga_ = (f32x4){0.f, 0.f, 0.f, 0.f};                           \
        ga_ = mfma16(wg_[fn][0], mnf[fi][0], ga_);                         \
        ga_ = mfma16(wg_[fn][1], mnf[fi][1], ga_);                         \
        ushort4 pk_;                                                       \
        pk_.x = f2bf(acc[fi][fn][0] * fast_sigmoid(ga_[0]));               \
        pk_.y = f2bf(acc[fi][fn][1] * fast_sigmoid(ga_[1]));               \
        pk_.z = f2bf(acc[fi][fn][2] * fast_sigmoid(ga_[2]));               \
        pk_.w = f2bf(acc[fi][fn][3] * fast_sigmoid(ga_[3]));               \
        *(ushort4*)(bb_ + row_ * 32 + ((fn * 16 + q * 4) ^ sw_)) = pk_;    \
        acc[fi][fn] = (f32x4){0.f, 0.f, 0.f, 0.f};                         \
      }                                                                    \
    }                                                                      \
    asm volatile("s_waitcnt lgkmcnt(0)" ::: "memory");                     \
    __builtin_amdgcn_sched_barrier(0);                                     \
    bf16x8 ogf_[2], wo_[4];                                                \
    _Pragma("unroll")                                                      \
    for (int fi = 0; fi < 2; ++fi) {                                       \
      const int row_ = fi * 16 + (lane & 15);                              \
      ogf_[fi] = ld8(bb_ + row_ * 32 + ((q * 8) ^ ((row_ & 3) << 3)));     \
    }                                                                      \
    _Pragma("unroll")                                                      \
    for (int cn = 0; cn < 4; ++cn)                                         \
      wo_[cn] = ld8(wof + ((cn * 8 + (hh)) * 64 + lane) * 8);              \
    _Pragma("unroll")                                                      \
    for (int cn = 0; cn < 4; ++cn)                                         \
      _Pragma("unroll")                                                    \
      for (int fi = 0; fi < 2; ++fi)                                       \
        oacc[cn][fi] = mfma16(wo_[cn], ogf_[fi], oacc[cn][fi]);            \
  } while (0)

  // prologue: tiles 0,1 in flight
  STAGE_P(gA, gB, 0);
  STAGE_P(gA + 32768, gB + 524288, 1);

  // heads 0..6: 16 static sub-iterations each (slot = u&3; stage slot (u+2)&3)
  for (int ho = 0; ho < 7; ++ho) {
    const char* pAh = gA + (size_t)(ho * 16) * 32768;
    const char* pBh = gB + (size_t)(ho * 16) * 524288;
    #pragma unroll
    for (int u = 0; u < 16; ++u) {
      asm volatile("s_waitcnt vmcnt(2)" ::: "memory");
      BARRIER();
      STAGE_P(pAh + (size_t)(u + 2) * 32768, pBh + (size_t)(u + 2) * 524288,
              (u + 2) & 3);
      COMPUTE(u & 3);
    }
    INTERLUDE(ho);
  }
  // head 7: stages for u=0..13 (last tile 127), peeled tail
  {
    const char* pAh = gA + (size_t)112 * 32768;
    const char* pBh = gB + (size_t)112 * 524288;
    #pragma unroll
    for (int u = 0; u < 14; ++u) {
      asm volatile("s_waitcnt vmcnt(2)" ::: "memory");
      BARRIER();
      STAGE_P(pAh + (size_t)(u + 2) * 32768, pBh + (size_t)(u + 2) * 524288,
              (u + 2) & 3);
      COMPUTE(u & 3);
    }
    asm volatile("s_waitcnt vmcnt(2)" ::: "memory");
    BARRIER();
    COMPUTE(2);
    asm volatile("s_waitcnt vmcnt(0)" ::: "memory");
    BARRIER();
    COMPUTE(3);
    INTERLUDE(7);
  }
#undef STAGE_P
#undef COMPUTE
#undef INTERLUDE

  // epilogue: write out[s][i][c] f32 (col=lane&15 -> i, row q*4+rg -> c)
  #pragma unroll
  for (int cn = 0; cn < 4; ++cn) {
    #pragma unroll
    for (int fi = 0; fi < 2; ++fi) {
      float* op = out + (size_t)(s * N_DIM + i0 + wr * 32 + fi * 16
                                 + (lane & 15)) * DM + cn * 16 + q * 4;
      *(f32x4*)op = oacc[cn][fi];
    }
  }
}

extern "C" void kernel_launch(void* const* d_in, const int* in_sizes, int n_in,
                              void* d_out, int out_size, void* d_ws, size_t ws_size,
                              hipStream_t stream) {
  const float* m   = (const float*)d_in[0];
  const float* z   = (const float*)d_in[1];
  const float* mnw = (const float*)d_in[2];
  const float* mnb = (const float*)d_in[3];
  const float* znw = (const float*)d_in[4];
  const float* znb = (const float*)d_in[5];
  const float* Wm  = (const float*)d_in[6];
  const float* Wg  = (const float*)d_in[7];
  const float* Wz  = (const float*)d_in[8];
  const float* Wo  = (const float*)d_in[9];
  float* out = (float*)d_out;
  char* ws = (char*)d_ws;

  // ws layout (bytes): wf 4MiB | vf 64MiB | (free 64MiB) | mn 16MiB |
  //                    wmg 64KiB | wof 32KiB | wzf 8KiB | t1c 64B
  // bws (8MiB f32) overlaps mn: k1a writes / k1b reads it BEFORE k2a writes mn.
  u16*   wbuf = (u16*)(ws);
  u16*   vf   = (u16*)(ws + ((size_t)4   << 20));
  u16*   mn   = (u16*)(ws + ((size_t)132 << 20));
  float* bws  = (float*)(ws + ((size_t)132 << 20));
  u16*   wmg  = (u16*)(ws + ((size_t)148 << 20));
  u16*   wof  = (u16*)(ws + ((size_t)148 << 20) + 65536);
  u16*   wzf  = (u16*)(ws + ((size_t)148 << 20) + 98304);
  float* t1c  = (float*)(ws + ((size_t)148 << 20) + 106496);

  k0_prep<<<209, 256, 0, stream>>>(Wm, Wg, Wo, znw, znb, Wz, wmg, wof, wzf, t1c);
  k1a_bias<<<dim3(8, 512), 256, 0, stream>>>(z, wzf, t1c, bws);
  k1b_softmax<<<1024, 256, 0, stream>>>(bws, wbuf);
  k2a_ln_m<<<512, 256, 0, stream>>>(m, mnw, mnb, mn);
  k2b_proj<<<2048, 256, 0, stream>>>(mn, wmg, vf);
  k3_fused<<<1024, 256, 0, stream>>>(wbuf, vf, mn, wmg, wof, out);
}